// Round 2
// baseline (3112.176 us; speedup 1.0000x reference)
//
#include <hip/hip_runtime.h>
#include <hip/hip_bf16.h>

#define BB 8
#define CC 64
#define HH 64
#define WW 64
#define LL 4096
#define DI 128
#define KK 4
#define NN 16
#define RR 4
#define XD 36   // R + 2N

__device__ __forceinline__ float softplusf(float x){ return x > 20.f ? x : log1pf(__expf(x)); }
__device__ __forceinline__ int p_of(int k, int t){
    int tt = (k & 2) ? (LL - 1 - t) : t;
    return (k & 1) ? ((tt & 63) * 64 + (tt >> 6)) : tt;
}

// ---------------- K1: LayerNorm(C) + in_proj -> xi (B,L,DI), zs=silu(z) (B,L,DI)
__global__ __launch_bounds__(256) void k1_ln_inproj(
    const float* __restrict__ x,     // (B,C,L)
    const float* __restrict__ ln1_g,
    const float* __restrict__ ln1_b,
    const float* __restrict__ ipw,   // (256,64)
    const float* __restrict__ ipb,   // (256)
    float* __restrict__ xi, float* __restrict__ zs)
{
    int pid = blockIdx.x;
    int b = pid >> 12, p = pid & 4095;
    __shared__ float lnx[64];
    int tid = threadIdx.x;
    if (tid < 64) {
        float v = x[((size_t)(b*CC + tid))*LL + p];
        float s = v, q = v*v;
        #pragma unroll
        for (int off = 32; off; off >>= 1){ s += __shfl_xor(s, off, 64); q += __shfl_xor(q, off, 64); }
        float mean = s * (1.0f/64.0f);
        float var  = q * (1.0f/64.0f) - mean*mean;
        float rstd = rsqrtf(var + 1e-5f);
        lnx[tid] = (v - mean) * rstd * ln1_g[tid] + ln1_b[tid];
    }
    __syncthreads();
    int d = tid;
    const float* wr = ipw + d*64;
    float acc = 0.f;
    #pragma unroll
    for (int c = 0; c < 64; c++) acc = fmaf(lnx[c], wr[c], acc);
    acc += ipb[d];
    size_t base = ((size_t)b*LL + p)*DI;
    if (d < DI) {
        xi[base + d] = acc;
    } else {
        float sg = 1.f / (1.f + __expf(-acc));
        zs[base + d - DI] = acc * sg;
    }
}

// ---------------- K2: depthwise 3x3 + SiLU -> xc (B,L,DI)
__global__ __launch_bounds__(256) void k2_dwconv(
    const float* __restrict__ xi,
    const float* __restrict__ cw,   // (128,3,3)
    const float* __restrict__ cb,
    float* __restrict__ xc)
{
    int idx = blockIdx.x*256 + threadIdx.x;   // (b*L+p)*128 + d
    int d = idx & 127;
    int bp = idx >> 7;
    int p = bp & 4095, b = bp >> 12;
    int h = p >> 6, w = p & 63;
    float acc = cb[d];
    #pragma unroll
    for (int ky = 0; ky < 3; ky++){
        int hh = h + ky - 1;
        if ((unsigned)hh >= 64u) continue;
        #pragma unroll
        for (int kx = 0; kx < 3; kx++){
            int ww = w + kx - 1;
            if ((unsigned)ww >= 64u) continue;
            acc = fmaf(xi[((size_t)(b*LL) + hh*64 + ww)*DI + d], cw[d*9 + ky*3 + kx], acc);
        }
    }
    float sg = 1.f / (1.f + __expf(-acc));
    xc[idx] = acc * sg;
}

// ---------------- K3: x_dbl = xproj(xc) scattered into sequence order (B,K,L,36)
__global__ __launch_bounds__(64) void k3_xdbl(
    const float* __restrict__ xc,
    const float* __restrict__ xpw,   // (4,36,128)
    float* __restrict__ xdbl)
{
    int pid = blockIdx.x;
    int b = pid >> 12, p = pid & 4095;
    __shared__ float row[128];
    int tid = threadIdx.x;
    row[tid]      = xc[((size_t)b*LL + p)*DI + tid];
    row[tid + 64] = xc[((size_t)b*LL + p)*DI + tid + 64];
    __syncthreads();
    int h = p >> 6, w = p & 63;
    int tT = w*64 + h;
    for (int co = tid; co < 144; co += 64){
        int k = co / 36, c = co % 36;
        int t = (k == 0) ? p : (k == 1) ? tT : (k == 2) ? (4095 - p) : (4095 - tT);
        const float* wr = xpw + (k*36 + c)*128;
        float acc = 0.f;
        #pragma unroll
        for (int dd = 0; dd < 128; dd++) acc = fmaf(row[dd], wr[dd], acc);
        xdbl[(((size_t)(b*KK + k))*LL + t)*XD + c] = acc;
    }
}

// ---------------- K4: selective scan, 4 directions accumulated into y (B,L,DI) via atomics
__global__ __launch_bounds__(256) void k4_scan(
    const float* __restrict__ xc, const float* __restrict__ xdbl,
    const float* __restrict__ dtw,    // (4,128,4)
    const float* __restrict__ dtb,    // (4,128)
    const float* __restrict__ A_logs, // (512,16)
    const float* __restrict__ Ds,     // (512)
    float* __restrict__ y)
{
    int bid = blockIdx.x;              // 256 blocks = 8b * 4k * 8grp
    int b = bid >> 5, k = (bid >> 3) & 3, grp = bid & 7;
    int d0 = grp * 16;
    int tid = threadIdx.x;
    int wv = tid >> 6, lane = tid & 63, n = lane & 15, j = lane >> 4;
    int d = d0 + wv*4 + j;
    int kd = k*DI + d;
    float An = -__expf(A_logs[kd*NN + n]);
    float Dv = Ds[kd];
    float w0 = dtw[kd*4+0], w1 = dtw[kd*4+1];
    float w2 = dtw[kd*4+2], w3 = dtw[kd*4+3];
    float bias = dtb[kd];
    __shared__ float sdbl[64*XD];
    __shared__ float su[64*16];
    const float* xdbase = xdbl + (size_t)(b*KK + k)*LL*XD;
    const float* xcb = xc + (size_t)b*LL*DI;
    float* yb = y + (size_t)b*LL*DI;
    float h = 0.f;
    for (int cc = 0; cc < 64; cc++){
        __syncthreads();
        const float* src = xdbase + (size_t)cc*64*XD;
        for (int i = tid; i < 64*XD; i += 256) sdbl[i] = src[i];
        for (int i = tid; i < 64*16; i += 256){
            int tl = i >> 4, ch = i & 15;
            int p = p_of(k, cc*64 + tl);
            su[i] = xcb[(size_t)p*DI + d0 + ch];
        }
        __syncthreads();
        for (int tl = 0; tl < 64; tl++){
            const float* rp = sdbl + tl*XD;
            float dtv = fmaf(rp[0], w0, fmaf(rp[1], w1, fmaf(rp[2], w2, fmaf(rp[3], w3, bias))));
            float dt = softplusf(dtv);
            float Bn = rp[4 + n], Cn = rp[20 + n];
            float u = su[tl*16 + wv*4 + j];
            h = fmaf(h, __expf(dt*An), dt*Bn*u);
            float yv = h * Cn;
            yv += __shfl_xor(yv, 1, 64);
            yv += __shfl_xor(yv, 2, 64);
            yv += __shfl_xor(yv, 4, 64);
            yv += __shfl_xor(yv, 8, 64);
            if (n == 0){
                int p = p_of(k, cc*64 + tl);
                atomicAdd(&yb[(size_t)p*DI + d], yv + Dv*u);
            }
        }
    }
}

// ---------------- K5: outnorm LN(DI) * silu(z) -> out_proj -> + residual xh -> xo (B,L,C)
__global__ __launch_bounds__(128) void k5_out(
    const float* __restrict__ y, const float* __restrict__ zs,
    const float* __restrict__ on_g, const float* __restrict__ on_b,
    const float* __restrict__ opw,  // (64,128)
    const float* __restrict__ opb,
    const float* __restrict__ x,    // (B,C,L)
    float* __restrict__ xo)
{
    int pid = blockIdx.x;
    int b = pid >> 12, p = pid & 4095;
    int d = threadIdx.x;
    __shared__ float v[128];
    __shared__ float red[4];
    size_t base = ((size_t)b*LL + p)*DI;
    float yv = y[base + d];
    float s = yv, q = yv*yv;
    #pragma unroll
    for (int off = 32; off; off >>= 1){ s += __shfl_xor(s, off, 64); q += __shfl_xor(q, off, 64); }
    if ((d & 63) == 0){ red[(d >> 6)*2] = s; red[(d >> 6)*2 + 1] = q; }
    __syncthreads();
    float mean = (red[0] + red[2]) * (1.f/128.f);
    float var  = (red[1] + red[3]) * (1.f/128.f) - mean*mean;
    float rstd = rsqrtf(var + 1e-5f);
    float yn = (yv - mean) * rstd * on_g[d] + on_b[d];
    v[d] = yn * zs[base + d];
    __syncthreads();
    if (d < 64){
        const float* wr = opw + d*DI;
        float acc = opb[d];
        #pragma unroll 8
        for (int dd = 0; dd < 128; dd++) acc = fmaf(v[dd], wr[dd], acc);
        acc += x[((size_t)(b*CC + d))*LL + p];
        xo[((size_t)b*LL + p)*CC + d] = acc;
    }
}

// ---------------- K6: channel LayerNorm over C -> cl (B,L,C)
__global__ __launch_bounds__(256) void k6_chln(
    const float* __restrict__ xo,
    const float* __restrict__ cn_g, const float* __restrict__ cn_b,
    float* __restrict__ cl)
{
    int pid = blockIdx.x*256 + threadIdx.x;
    if (pid >= BB*LL) return;
    const float* r = xo + (size_t)pid*CC;
    float s = 0.f, q = 0.f;
    #pragma unroll 8
    for (int c = 0; c < 64; c++){ float v = r[c]; s += v; q += v*v; }
    float mean = s * (1.f/64.f);
    float var  = q * (1.f/64.f) - mean*mean;
    float rstd = rsqrtf(var + 1e-6f);
    float* o = cl + (size_t)pid*CC;
    #pragma unroll 8
    for (int c = 0; c < 64; c++) o[c] = (r[c] - mean)*rstd*cn_g[c] + cn_b[c];
}

// ---------------- K7: max pools 2/4/8 for SAFM branches 1..3
__global__ __launch_bounds__(256) void k7_pools(const float* __restrict__ cl, float* __restrict__ pools)
{
    int idx = blockIdx.x*256 + threadIdx.x;
    int g, S, base;
    if (idx < 131072)      { g = 1; S = 32; base = 0; }
    else if (idx < 163840) { g = 2; S = 16; base = 131072; idx -= 131072; }
    else if (idx < 172032) { g = 3; S = 8;  base = 163840; idx -= 163840; }
    else return;
    int pw = idx % S; idx /= S;
    int ph = idx % S; idx /= S;
    int j = idx & 15; int b = idx >> 4;
    int kk = 64 / S;
    int c = g*16 + j;
    float m = -1e30f;
    for (int dy = 0; dy < kk; dy++)
        for (int dx = 0; dx < kk; dx++){
            int h = ph*kk + dy, w = pw*kk + dx;
            m = fmaxf(m, cl[((size_t)(b*LL) + h*64 + w)*CC + c]);
        }
    pools[base + ((size_t)(b*16 + j)*S + ph)*S + pw] = m;
}

// ---------------- K8: SAFM branch depthwise convs (+ upsample by recompute) -> cat (B,L,C)
__global__ __launch_bounds__(256) void k8_mfr(
    const float* __restrict__ cl, const float* __restrict__ pools,
    const float* __restrict__ mfr_w,  // (4,16,3,3)
    const float* __restrict__ mfr_b,  // (4,16)
    float* __restrict__ cat)
{
    int idx = blockIdx.x*256 + threadIdx.x;   // (b*L+p)*64 + c
    int c = idx & 63; int bp = idx >> 6;
    int p = bp & 4095, b = bp >> 12;
    int g = c >> 4, j = c & 15;
    int h = p >> 6, w = p & 63;
    float acc = mfr_b[g*16 + j];
    const float* wr = mfr_w + (g*16 + j)*9;
    if (g == 0){
        #pragma unroll
        for (int ky = 0; ky < 3; ky++){
            int hh = h + ky - 1; if ((unsigned)hh >= 64u) continue;
            #pragma unroll
            for (int kx = 0; kx < 3; kx++){
                int ww = w + kx - 1; if ((unsigned)ww >= 64u) continue;
                acc = fmaf(cl[((size_t)(b*LL) + hh*64 + ww)*CC + c], wr[ky*3 + kx], acc);
            }
        }
    } else {
        int S = 64 >> g;
        int ph = h >> g, pw = w >> g;
        int base = (g == 1) ? 0 : ((g == 2) ? 131072 : 163840);
        const float* P = pools + base + (size_t)(b*16 + j)*S*S;
        #pragma unroll
        for (int ky = 0; ky < 3; ky++){
            int hh = ph + ky - 1; if ((unsigned)hh >= (unsigned)S) continue;
            #pragma unroll
            for (int kx = 0; kx < 3; kx++){
                int ww = pw + kx - 1; if ((unsigned)ww >= (unsigned)S) continue;
                acc = fmaf(P[hh*S + ww], wr[ky*3 + kx], acc);
            }
        }
    }
    cat[idx] = acc;
}

// ---------------- K9: 1x1 aggregation + GELU * cl + residual -> out (B,C,L) f32
__global__ __launch_bounds__(64) void k9_agg(
    const float* __restrict__ cat, const float* __restrict__ cl, const float* __restrict__ xo,
    const float* __restrict__ agw,   // (64,64)
    const float* __restrict__ agb,
    float* __restrict__ out)
{
    int pid = blockIdx.x;
    int b = pid >> 12, p = pid & 4095;
    int o = threadIdx.x;
    __shared__ float crow[64];
    size_t base = ((size_t)b*LL + p)*CC;
    crow[o] = cat[base + o];
    __syncthreads();
    const float* wr = agw + o*64;
    float acc = agb[o];
    #pragma unroll 8
    for (int c = 0; c < 64; c++) acc = fmaf(crow[c], wr[c], acc);
    float gl = 0.5f*acc*(1.f + erff(acc*0.70710678118f));
    float res = xo[base + o] + gl*cl[base + o];
    out[((size_t)(b*CC + o))*LL + p] = res;
}

extern "C" void kernel_launch(void* const* d_in, const int* in_sizes, int n_in,
                              void* d_out, int out_size, void* d_ws, size_t ws_size,
                              hipStream_t stream)
{
    const float* x       = (const float*)d_in[0];
    const float* ln1_g   = (const float*)d_in[1];
    const float* ln1_b   = (const float*)d_in[2];
    const float* ipw     = (const float*)d_in[3];
    const float* ipb     = (const float*)d_in[4];
    const float* conv_w  = (const float*)d_in[5];
    const float* conv_b  = (const float*)d_in[6];
    const float* xpw     = (const float*)d_in[7];
    const float* dtw     = (const float*)d_in[8];
    const float* dtb     = (const float*)d_in[9];
    const float* A_logs  = (const float*)d_in[10];
    const float* Ds      = (const float*)d_in[11];
    const float* on_g    = (const float*)d_in[12];
    const float* on_b    = (const float*)d_in[13];
    const float* opw     = (const float*)d_in[14];
    const float* opb     = (const float*)d_in[15];
    const float* mfr_w   = (const float*)d_in[16];
    const float* mfr_b   = (const float*)d_in[17];
    const float* agw     = (const float*)d_in[18];
    const float* agb     = (const float*)d_in[19];
    const float* cn_g    = (const float*)d_in[20];
    const float* cn_b    = (const float*)d_in[21];
    float* out = (float*)d_out;

    float* ws = (float*)d_ws;
    float* xi    = ws;               // 4,194,304 floats ; later reused as y
    float* zs    = ws + 4194304;     // 4,194,304 ; later reused as cat
    float* xc    = ws + 8388608;     // 4,194,304 ; later reused as xo + pools
    float* xdbl  = ws + 12582912;    // 4,718,592 ; later reused as cl
    float* y     = xi;
    float* xo    = xc;
    float* pools = xc + 2097152;
    float* cl    = xdbl;
    float* cat   = zs;

    // SS2D
    hipLaunchKernelGGL(k1_ln_inproj, dim3(BB*LL), dim3(256), 0, stream,
                       x, ln1_g, ln1_b, ipw, ipb, xi, zs);
    hipLaunchKernelGGL(k2_dwconv, dim3(BB*LL*DI/256), dim3(256), 0, stream,
                       xi, conv_w, conv_b, xc);
    hipLaunchKernelGGL(k3_xdbl, dim3(BB*LL), dim3(64), 0, stream,
                       xc, xpw, xdbl);
    hipMemsetAsync(y, 0, (size_t)BB*LL*DI*sizeof(float), stream);
    hipLaunchKernelGGL(k4_scan, dim3(256), dim3(256), 0, stream,
                       xc, xdbl, dtw, dtb, A_logs, Ds, y);
    hipLaunchKernelGGL(k5_out, dim3(BB*LL), dim3(128), 0, stream,
                       y, zs, on_g, on_b, opw, opb, x, xo);
    // SAFM
    hipLaunchKernelGGL(k6_chln, dim3((BB*LL + 255)/256), dim3(256), 0, stream,
                       xo, cn_g, cn_b, cl);
    hipLaunchKernelGGL(k7_pools, dim3((172032 + 255)/256), dim3(256), 0, stream,
                       cl, pools);
    hipLaunchKernelGGL(k8_mfr, dim3(BB*LL*CC/256), dim3(256), 0, stream,
                       cl, pools, mfr_w, mfr_b, cat);
    hipLaunchKernelGGL(k9_agg, dim3(BB*LL), dim3(64), 0, stream,
                       cat, cl, xo, agw, agb, out);
}

// Round 3
// 1347.835 us; speedup vs baseline: 2.3090x; 2.3090x over previous
//
#include <hip/hip_runtime.h>
#include <hip/hip_bf16.h>

#define BB 8
#define CC 64
#define HH 64
#define WW 64
#define LL 4096
#define DI 128
#define KK 4
#define NN 16
#define RR 4
#define XD 36   // R + 2N

__device__ __forceinline__ float softplusf(float x){ return x > 20.f ? x : log1pf(__expf(x)); }
__device__ __forceinline__ int p_of(int k, int t){
    int tt = (k & 2) ? (LL - 1 - t) : t;
    return (k & 1) ? ((tt & 63) * 64 + (tt >> 6)) : tt;
}

// DPP butterfly add over the 16-lane row: masks {1,2,7,15} span all 4 bits.
template<int CTRL>
__device__ __forceinline__ float dpp_xadd(float v){
    int t = __builtin_amdgcn_update_dpp(0, __float_as_int(v), CTRL, 0xF, 0xF, true);
    return v + __int_as_float(t);
}

// ---------------- K1: LayerNorm(C) + in_proj -> xi (B,L,DI), zs=silu(z) (B,L,DI)
__global__ __launch_bounds__(256) void k1_ln_inproj(
    const float* __restrict__ x,     // (B,C,L)
    const float* __restrict__ ln1_g,
    const float* __restrict__ ln1_b,
    const float* __restrict__ ipw,   // (256,64)
    const float* __restrict__ ipb,   // (256)
    float* __restrict__ xi, float* __restrict__ zs)
{
    int pid = blockIdx.x;
    int b = pid >> 12, p = pid & 4095;
    __shared__ float lnx[64];
    int tid = threadIdx.x;
    if (tid < 64) {
        float v = x[((size_t)(b*CC + tid))*LL + p];
        float s = v, q = v*v;
        #pragma unroll
        for (int off = 32; off; off >>= 1){ s += __shfl_xor(s, off, 64); q += __shfl_xor(q, off, 64); }
        float mean = s * (1.0f/64.0f);
        float var  = q * (1.0f/64.0f) - mean*mean;
        float rstd = rsqrtf(var + 1e-5f);
        lnx[tid] = (v - mean) * rstd * ln1_g[tid] + ln1_b[tid];
    }
    __syncthreads();
    int d = tid;
    const float* wr = ipw + d*64;
    float acc = 0.f;
    #pragma unroll
    for (int c = 0; c < 64; c++) acc = fmaf(lnx[c], wr[c], acc);
    acc += ipb[d];
    size_t base = ((size_t)b*LL + p)*DI;
    if (d < DI) {
        xi[base + d] = acc;
    } else {
        float sg = 1.f / (1.f + __expf(-acc));
        zs[base + d - DI] = acc * sg;
    }
}

// ---------------- K2: depthwise 3x3 + SiLU -> xc (B,L,DI)
__global__ __launch_bounds__(256) void k2_dwconv(
    const float* __restrict__ xi,
    const float* __restrict__ cw,   // (128,3,3)
    const float* __restrict__ cb,
    float* __restrict__ xc)
{
    int idx = blockIdx.x*256 + threadIdx.x;   // (b*L+p)*128 + d
    int d = idx & 127;
    int bp = idx >> 7;
    int p = bp & 4095, b = bp >> 12;
    int h = p >> 6, w = p & 63;
    float acc = cb[d];
    #pragma unroll
    for (int ky = 0; ky < 3; ky++){
        int hh = h + ky - 1;
        if ((unsigned)hh >= 64u) continue;
        #pragma unroll
        for (int kx = 0; kx < 3; kx++){
            int ww = w + kx - 1;
            if ((unsigned)ww >= 64u) continue;
            acc = fmaf(xi[((size_t)(b*LL) + hh*64 + ww)*DI + d], cw[d*9 + ky*3 + kx], acc);
        }
    }
    float sg = 1.f / (1.f + __expf(-acc));
    xc[idx] = acc * sg;
}

// ---------------- K3: x_dbl = xproj(xc) scattered into sequence order (B,K,L,36)
__global__ __launch_bounds__(64) void k3_xdbl(
    const float* __restrict__ xc,
    const float* __restrict__ xpw,   // (4,36,128)
    float* __restrict__ xdbl)
{
    int pid = blockIdx.x;
    int b = pid >> 12, p = pid & 4095;
    __shared__ float row[128];
    int tid = threadIdx.x;
    row[tid]      = xc[((size_t)b*LL + p)*DI + tid];
    row[tid + 64] = xc[((size_t)b*LL + p)*DI + tid + 64];
    __syncthreads();
    int h = p >> 6, w = p & 63;
    int tT = w*64 + h;
    for (int co = tid; co < 144; co += 64){
        int k = co / 36, c = co % 36;
        int t = (k == 0) ? p : (k == 1) ? tT : (k == 2) ? (4095 - p) : (4095 - tT);
        const float* wr = xpw + (k*36 + c)*128;
        float acc = 0.f;
        #pragma unroll
        for (int dd = 0; dd < 128; dd++) acc = fmaf(row[dd], wr[dd], acc);
        xdbl[(((size_t)(b*KK + k))*LL + t)*XD + c] = acc;
    }
}

// ---------------- K4: selective scan (rewritten)
// Block = (b, k, 16-channel group). Lane: n = lane&15, j = lane>>4, ch = wv*4+j.
// Staging precomputes dt (softplus) and dt*u per (t,ch); inner loop is
// ds_read_b64 + 2x ds_read_b32 + exp + fma chain + DPP butterfly over n.
__global__ __launch_bounds__(256) void k4_scan(
    const float* __restrict__ xc, const float* __restrict__ xdbl,
    const float* __restrict__ dtw,    // (4,128,4)
    const float* __restrict__ dtb,    // (4,128)
    const float* __restrict__ A_logs, // (512,16)
    const float* __restrict__ Ds,     // (512)
    float* __restrict__ y)
{
    int bid = blockIdx.x;              // 256 blocks = 8b * 4k * 8grp
    int b = bid >> 5, k = (bid >> 3) & 3, grp = bid & 7;
    int d0 = grp * 16;
    int tid = threadIdx.x;
    int wv = tid >> 6, lane = tid & 63, n = lane & 15, j = lane >> 4;
    int ch = wv*4 + j;
    int d = d0 + ch;
    int kd = k*DI + d;
    float An = -__expf(A_logs[kd*NN + n]);

    // per-thread staging params (ch_s = tid&15 mapping for derived compute)
    int ch_s = tid & 15;
    int kds = k*DI + d0 + ch_s;
    float w0s = dtw[kds*4+0], w1s = dtw[kds*4+1], w2s = dtw[kds*4+2], w3s = dtw[kds*4+3];
    float bs  = dtb[kds];
    float Dvs = Ds[kds];

    __shared__ float sraw[64*XD];    // raw xdbl rows (B at +4, C at +20)
    __shared__ float sdd[64*16*2];   // (dt, dt*u) interleaved per (t,ch)
    __shared__ float sdy[64*17];     // Dv*u per (t,ch), padded stride 17

    const float* xdbase = xdbl + (size_t)(b*KK + k)*LL*XD;
    const float* xcb = xc + (size_t)b*LL*DI;
    float* yb = y + (size_t)b*LL*DI;
    float h = 0.f;

    for (int cc = 0; cc < 64; cc++){
        __syncthreads();   // previous inner loop done reading LDS
        const float* src = xdbase + (size_t)cc*64*XD;
        // stage raw rows (16B vector copies; 64*36 floats = 576 float4)
        for (int i2 = tid; i2 < 576; i2 += 256){
            float4 v = ((const float4*)src)[i2];
            ((float4*)sraw)[i2] = v;
        }
        // derived: dt = softplus(x_dbl[0:4]·w + b); store (dt, dt*u) and Dv*u
        #pragma unroll
        for (int it = 0; it < 4; it++){
            int idx = tid + it*256;
            int t = idx >> 4;
            int pu = p_of(k, cc*64 + t);
            float u = xcb[(size_t)pu*DI + d0 + ch_s];
            float4 xr = *(const float4*)(src + t*XD);
            float dtr = fmaf(xr.x, w0s, fmaf(xr.y, w1s, fmaf(xr.z, w2s, fmaf(xr.w, w3s, bs))));
            float dt = softplusf(dtr);
            sdd[idx*2]     = dt;
            sdd[idx*2 + 1] = dt*u;
            sdy[t*17 + ch_s] = Dvs * u;
        }
        __syncthreads();

        #pragma unroll
        for (int tg = 0; tg < 4; tg++){
            float myv = 0.f;
            #pragma unroll
            for (int it = 0; it < 16; it++){
                int t = tg*16 + it;
                float dt = sdd[(t*16 + ch)*2];
                float du = sdd[(t*16 + ch)*2 + 1];
                float Bn = sraw[t*XD + 4 + n];
                float Cn = sraw[t*XD + 20 + n];
                float e = __expf(dt * An);
                h = fmaf(h, e, du * Bn);
                float yv = h * Cn;
                yv = dpp_xadd<0xB1>(yv);   // xor 1 (quad_perm [1,0,3,2])
                yv = dpp_xadd<0x4E>(yv);   // xor 2 (quad_perm [2,3,0,1])
                yv = dpp_xadd<0x141>(yv);  // xor 7 (row_half_mirror)
                yv = dpp_xadd<0x140>(yv);  // xor 15 (row_mirror)
                if (it == n) myv = yv;     // lane n keeps t = tg*16+n
            }
            int t = tg*16 + n;
            float yt = myv + sdy[t*17 + ch];
            int p = p_of(k, cc*64 + t);
            atomicAdd(&yb[(size_t)p*DI + d], yt);   // 64 distinct (t,ch) lanes
        }
    }
}

// ---------------- K5: outnorm LN(DI) * silu(z) -> out_proj -> + residual xh -> xo (B,L,C)
__global__ __launch_bounds__(128) void k5_out(
    const float* __restrict__ y, const float* __restrict__ zs,
    const float* __restrict__ on_g, const float* __restrict__ on_b,
    const float* __restrict__ opw,  // (64,128)
    const float* __restrict__ opb,
    const float* __restrict__ x,    // (B,C,L)
    float* __restrict__ xo)
{
    int pid = blockIdx.x;
    int b = pid >> 12, p = pid & 4095;
    int d = threadIdx.x;
    __shared__ float v[128];
    __shared__ float red[4];
    size_t base = ((size_t)b*LL + p)*DI;
    float yv = y[base + d];
    float s = yv, q = yv*yv;
    #pragma unroll
    for (int off = 32; off; off >>= 1){ s += __shfl_xor(s, off, 64); q += __shfl_xor(q, off, 64); }
    if ((d & 63) == 0){ red[(d >> 6)*2] = s; red[(d >> 6)*2 + 1] = q; }
    __syncthreads();
    float mean = (red[0] + red[2]) * (1.f/128.f);
    float var  = (red[1] + red[3]) * (1.f/128.f) - mean*mean;
    float rstd = rsqrtf(var + 1e-5f);
    float yn = (yv - mean) * rstd * on_g[d] + on_b[d];
    v[d] = yn * zs[base + d];
    __syncthreads();
    if (d < 64){
        const float* wr = opw + d*DI;
        float acc = opb[d];
        #pragma unroll 8
        for (int dd = 0; dd < 128; dd++) acc = fmaf(v[dd], wr[dd], acc);
        acc += x[((size_t)(b*CC + d))*LL + p];
        xo[((size_t)b*LL + p)*CC + d] = acc;
    }
}

// ---------------- K6: channel LayerNorm over C -> cl (B,L,C)
__global__ __launch_bounds__(256) void k6_chln(
    const float* __restrict__ xo,
    const float* __restrict__ cn_g, const float* __restrict__ cn_b,
    float* __restrict__ cl)
{
    int pid = blockIdx.x*256 + threadIdx.x;
    if (pid >= BB*LL) return;
    const float* r = xo + (size_t)pid*CC;
    float s = 0.f, q = 0.f;
    #pragma unroll 8
    for (int c = 0; c < 64; c++){ float v = r[c]; s += v; q += v*v; }
    float mean = s * (1.f/64.f);
    float var  = q * (1.f/64.f) - mean*mean;
    float rstd = rsqrtf(var + 1e-6f);
    float* o = cl + (size_t)pid*CC;
    #pragma unroll 8
    for (int c = 0; c < 64; c++) o[c] = (r[c] - mean)*rstd*cn_g[c] + cn_b[c];
}

// ---------------- K7: max pools 2/4/8 for SAFM branches 1..3
__global__ __launch_bounds__(256) void k7_pools(const float* __restrict__ cl, float* __restrict__ pools)
{
    int idx = blockIdx.x*256 + threadIdx.x;
    int g, S, base;
    if (idx < 131072)      { g = 1; S = 32; base = 0; }
    else if (idx < 163840) { g = 2; S = 16; base = 131072; idx -= 131072; }
    else if (idx < 172032) { g = 3; S = 8;  base = 163840; idx -= 163840; }
    else return;
    int pw = idx % S; idx /= S;
    int ph = idx % S; idx /= S;
    int j = idx & 15; int b = idx >> 4;
    int kk = 64 / S;
    int c = g*16 + j;
    float m = -1e30f;
    for (int dy = 0; dy < kk; dy++)
        for (int dx = 0; dx < kk; dx++){
            int h = ph*kk + dy, w = pw*kk + dx;
            m = fmaxf(m, cl[((size_t)(b*LL) + h*64 + w)*CC + c]);
        }
    pools[base + ((size_t)(b*16 + j)*S + ph)*S + pw] = m;
}

// ---------------- K8: SAFM branch depthwise convs (+ upsample by recompute) -> cat (B,L,C)
__global__ __launch_bounds__(256) void k8_mfr(
    const float* __restrict__ cl, const float* __restrict__ pools,
    const float* __restrict__ mfr_w,  // (4,16,3,3)
    const float* __restrict__ mfr_b,  // (4,16)
    float* __restrict__ cat)
{
    int idx = blockIdx.x*256 + threadIdx.x;   // (b*L+p)*64 + c
    int c = idx & 63; int bp = idx >> 6;
    int p = bp & 4095, b = bp >> 12;
    int g = c >> 4, j = c & 15;
    int h = p >> 6, w = p & 63;
    float acc = mfr_b[g*16 + j];
    const float* wr = mfr_w + (g*16 + j)*9;
    if (g == 0){
        #pragma unroll
        for (int ky = 0; ky < 3; ky++){
            int hh = h + ky - 1; if ((unsigned)hh >= 64u) continue;
            #pragma unroll
            for (int kx = 0; kx < 3; kx++){
                int ww = w + kx - 1; if ((unsigned)ww >= 64u) continue;
                acc = fmaf(cl[((size_t)(b*LL) + hh*64 + ww)*CC + c], wr[ky*3 + kx], acc);
            }
        }
    } else {
        int S = 64 >> g;
        int ph = h >> g, pw = w >> g;
        int base = (g == 1) ? 0 : ((g == 2) ? 131072 : 163840);
        const float* P = pools + base + (size_t)(b*16 + j)*S*S;
        #pragma unroll
        for (int ky = 0; ky < 3; ky++){
            int hh = ph + ky - 1; if ((unsigned)hh >= (unsigned)S) continue;
            #pragma unroll
            for (int kx = 0; kx < 3; kx++){
                int ww = pw + kx - 1; if ((unsigned)ww >= (unsigned)S) continue;
                acc = fmaf(P[hh*S + ww], wr[ky*3 + kx], acc);
            }
        }
    }
    cat[idx] = acc;
}

// ---------------- K9: 1x1 aggregation + GELU * cl + residual -> out (B,C,L) f32
__global__ __launch_bounds__(64) void k9_agg(
    const float* __restrict__ cat, const float* __restrict__ cl, const float* __restrict__ xo,
    const float* __restrict__ agw,   // (64,64)
    const float* __restrict__ agb,
    float* __restrict__ out)
{
    int pid = blockIdx.x;
    int b = pid >> 12, p = pid & 4095;
    int o = threadIdx.x;
    __shared__ float crow[64];
    size_t base = ((size_t)b*LL + p)*CC;
    crow[o] = cat[base + o];
    __syncthreads();
    const float* wr = agw + o*64;
    float acc = agb[o];
    #pragma unroll 8
    for (int c = 0; c < 64; c++) acc = fmaf(crow[c], wr[c], acc);
    float gl = 0.5f*acc*(1.f + erff(acc*0.70710678118f));
    float res = xo[base + o] + gl*cl[base + o];
    out[((size_t)(b*CC + o))*LL + p] = res;
}

extern "C" void kernel_launch(void* const* d_in, const int* in_sizes, int n_in,
                              void* d_out, int out_size, void* d_ws, size_t ws_size,
                              hipStream_t stream)
{
    const float* x       = (const float*)d_in[0];
    const float* ln1_g   = (const float*)d_in[1];
    const float* ln1_b   = (const float*)d_in[2];
    const float* ipw     = (const float*)d_in[3];
    const float* ipb     = (const float*)d_in[4];
    const float* conv_w  = (const float*)d_in[5];
    const float* conv_b  = (const float*)d_in[6];
    const float* xpw     = (const float*)d_in[7];
    const float* dtw     = (const float*)d_in[8];
    const float* dtb     = (const float*)d_in[9];
    const float* A_logs  = (const float*)d_in[10];
    const float* Ds      = (const float*)d_in[11];
    const float* on_g    = (const float*)d_in[12];
    const float* on_b    = (const float*)d_in[13];
    const float* opw     = (const float*)d_in[14];
    const float* opb     = (const float*)d_in[15];
    const float* mfr_w   = (const float*)d_in[16];
    const float* mfr_b   = (const float*)d_in[17];
    const float* agw     = (const float*)d_in[18];
    const float* agb     = (const float*)d_in[19];
    const float* cn_g    = (const float*)d_in[20];
    const float* cn_b    = (const float*)d_in[21];
    float* out = (float*)d_out;

    float* ws = (float*)d_ws;
    float* xi    = ws;               // 4,194,304 floats ; later reused as y
    float* zs    = ws + 4194304;     // 4,194,304 ; later reused as cat
    float* xc    = ws + 8388608;     // 4,194,304 ; later reused as xo + pools
    float* xdbl  = ws + 12582912;    // 4,718,592 ; later reused as cl
    float* y     = xi;
    float* xo    = xc;
    float* pools = xc + 2097152;
    float* cl    = xdbl;
    float* cat   = zs;

    // SS2D
    hipLaunchKernelGGL(k1_ln_inproj, dim3(BB*LL), dim3(256), 0, stream,
                       x, ln1_g, ln1_b, ipw, ipb, xi, zs);
    hipLaunchKernelGGL(k2_dwconv, dim3(BB*LL*DI/256), dim3(256), 0, stream,
                       xi, conv_w, conv_b, xc);
    hipLaunchKernelGGL(k3_xdbl, dim3(BB*LL), dim3(64), 0, stream,
                       xc, xpw, xdbl);
    hipMemsetAsync(y, 0, (size_t)BB*LL*DI*sizeof(float), stream);
    hipLaunchKernelGGL(k4_scan, dim3(256), dim3(256), 0, stream,
                       xc, xdbl, dtw, dtb, A_logs, Ds, y);
    hipLaunchKernelGGL(k5_out, dim3(BB*LL), dim3(128), 0, stream,
                       y, zs, on_g, on_b, opw, opb, x, xo);
    // SAFM
    hipLaunchKernelGGL(k6_chln, dim3((BB*LL + 255)/256), dim3(256), 0, stream,
                       xo, cn_g, cn_b, cl);
    hipLaunchKernelGGL(k7_pools, dim3((172032 + 255)/256), dim3(256), 0, stream,
                       cl, pools);
    hipLaunchKernelGGL(k8_mfr, dim3(BB*LL*CC/256), dim3(256), 0, stream,
                       cl, pools, mfr_w, mfr_b, cat);
    hipLaunchKernelGGL(k9_agg, dim3(BB*LL), dim3(64), 0, stream,
                       cat, cl, xo, agw, agb, out);
}

// Round 4
// 1068.083 us; speedup vs baseline: 2.9138x; 1.2619x over previous
//
#include <hip/hip_runtime.h>
#include <hip/hip_bf16.h>

#define BB 8
#define CC 64
#define HH 64
#define WW 64
#define LL 4096
#define DI 128
#define KK 4
#define NN 16
#define RR 4
#define XD 36   // R + 2N
#define GG 64   // scan chunks
#define TT 64   // timesteps per chunk

__device__ __forceinline__ float softplusf(float x){
    // stable: max(x,0) + log(1+exp(-|x|))
    return fmaxf(x, 0.f) + __logf(1.f + __expf(-fabsf(x)));
}
__device__ __forceinline__ int p_of(int k, int t){
    int tt = (k & 2) ? (LL - 1 - t) : t;
    return (k & 1) ? ((tt & 63) * 64 + (tt >> 6)) : tt;
}

// DPP butterfly add over the 16-lane row (serial fallback kernel only)
template<int CTRL>
__device__ __forceinline__ float dpp_xadd(float v){
    int t = __builtin_amdgcn_update_dpp(0, __float_as_int(v), CTRL, 0xF, 0xF, true);
    return v + __int_as_float(t);
}

// ---------------- K1: LayerNorm(C) + in_proj -> xi (B,L,DI), zs=silu(z) (B,L,DI)
__global__ __launch_bounds__(256) void k1_ln_inproj(
    const float* __restrict__ x,     // (B,C,L)
    const float* __restrict__ ln1_g,
    const float* __restrict__ ln1_b,
    const float* __restrict__ ipw,   // (256,64)
    const float* __restrict__ ipb,   // (256)
    float* __restrict__ xi, float* __restrict__ zs)
{
    int pid = blockIdx.x;
    int b = pid >> 12, p = pid & 4095;
    __shared__ float lnx[64];
    int tid = threadIdx.x;
    if (tid < 64) {
        float v = x[((size_t)(b*CC + tid))*LL + p];
        float s = v, q = v*v;
        #pragma unroll
        for (int off = 32; off; off >>= 1){ s += __shfl_xor(s, off, 64); q += __shfl_xor(q, off, 64); }
        float mean = s * (1.0f/64.0f);
        float var  = q * (1.0f/64.0f) - mean*mean;
        float rstd = rsqrtf(var + 1e-5f);
        lnx[tid] = (v - mean) * rstd * ln1_g[tid] + ln1_b[tid];
    }
    __syncthreads();
    int d = tid;
    const float4* wr4 = (const float4*)(ipw + d*64);
    const float4* ln4 = (const float4*)lnx;
    float acc = 0.f;
    #pragma unroll
    for (int i = 0; i < 16; i++){
        float4 a = ln4[i], w = wr4[i];
        acc = fmaf(a.x, w.x, acc); acc = fmaf(a.y, w.y, acc);
        acc = fmaf(a.z, w.z, acc); acc = fmaf(a.w, w.w, acc);
    }
    acc += ipb[d];
    size_t base = ((size_t)b*LL + p)*DI;
    if (d < DI) {
        xi[base + d] = acc;
    } else {
        float sg = 1.f / (1.f + __expf(-acc));
        zs[base + d - DI] = acc * sg;
    }
}

// ---------------- K2: depthwise 3x3 + SiLU -> xc (B,L,DI)
__global__ __launch_bounds__(256) void k2_dwconv(
    const float* __restrict__ xi,
    const float* __restrict__ cw,   // (128,3,3)
    const float* __restrict__ cb,
    float* __restrict__ xc)
{
    int idx = blockIdx.x*256 + threadIdx.x;   // (b*L+p)*128 + d
    int d = idx & 127;
    int bp = idx >> 7;
    int p = bp & 4095, b = bp >> 12;
    int h = p >> 6, w = p & 63;
    float acc = cb[d];
    #pragma unroll
    for (int ky = 0; ky < 3; ky++){
        int hh = h + ky - 1;
        if ((unsigned)hh >= 64u) continue;
        #pragma unroll
        for (int kx = 0; kx < 3; kx++){
            int ww = w + kx - 1;
            if ((unsigned)ww >= 64u) continue;
            acc = fmaf(xi[((size_t)(b*LL) + hh*64 + ww)*DI + d], cw[d*9 + ky*3 + kx], acc);
        }
    }
    float sg = 1.f / (1.f + __expf(-acc));
    xc[idx] = acc * sg;
}

// ---------------- K3: x_dbl = xproj(xc) scattered into sequence order (B,K,L,36)
__global__ __launch_bounds__(64) void k3_xdbl(
    const float* __restrict__ xc,
    const float* __restrict__ xpw,   // (4,36,128)
    float* __restrict__ xdbl)
{
    int pid = blockIdx.x;
    int b = pid >> 12, p = pid & 4095;
    __shared__ float row[128];
    int tid = threadIdx.x;
    row[tid]      = xc[((size_t)b*LL + p)*DI + tid];
    row[tid + 64] = xc[((size_t)b*LL + p)*DI + tid + 64];
    __syncthreads();
    int h = p >> 6, w = p & 63;
    int tT = w*64 + h;
    const float4* row4 = (const float4*)row;
    for (int co = tid; co < 144; co += 64){
        int k = co / 36, c = co % 36;
        int t = (k == 0) ? p : (k == 1) ? tT : (k == 2) ? (4095 - p) : (4095 - tT);
        const float4* wr4 = (const float4*)(xpw + (k*36 + c)*128);
        float acc = 0.f;
        #pragma unroll
        for (int i = 0; i < 32; i++){
            float4 a = row4[i], wv = wr4[i];
            acc = fmaf(a.x, wv.x, acc); acc = fmaf(a.y, wv.y, acc);
            acc = fmaf(a.z, wv.z, acc); acc = fmaf(a.w, wv.w, acc);
        }
        xdbl[(((size_t)(b*KK + k))*LL + t)*XD + c] = acc;
    }
}

// ---------------- K4a: per-chunk local scan -> H (local final h), P (chunk decay)
// block = (b,k,chunk), 128 threads (thread = d, owns all 16 n)
__global__ __launch_bounds__(128, 4) void k4a_local(
    const float* __restrict__ xc, const float* __restrict__ xdbl,
    const float* __restrict__ dtw, const float* __restrict__ dtb,
    const float* __restrict__ A_logs,
    float* __restrict__ Pbuf, float* __restrict__ Hbuf)
{
    int bid = blockIdx.x;            // ((b*4+k)*64+cc)
    int cc = bid & 63, k = (bid >> 6) & 3, b = bid >> 8;
    int d = threadIdx.x;
    int kd = k*DI + d;
    float4 wv4 = *(const float4*)(dtw + kd*4);
    float bias = dtb[kd];
    float An[16];
    {
        const float4* al = (const float4*)(A_logs + kd*16);
        #pragma unroll
        for (int i = 0; i < 4; i++){
            float4 a = al[i];
            An[i*4+0] = -__expf(a.x); An[i*4+1] = -__expf(a.y);
            An[i*4+2] = -__expf(a.z); An[i*4+3] = -__expf(a.w);
        }
    }
    __shared__ float sraw[TT*XD];
    const float* src = xdbl + ((size_t)(b*KK + k)*LL + cc*TT)*XD;
    for (int i = threadIdx.x; i < TT*XD/4; i += 128)
        ((float4*)sraw)[i] = ((const float4*)src)[i];
    __syncthreads();

    const float* xcb = xc + (size_t)b*LL*DI;
    float h[16];
    #pragma unroll
    for (int i = 0; i < 16; i++) h[i] = 0.f;
    float Sdt = 0.f;
    for (int t = 0; t < TT; t++){
        const float* rp = sraw + t*XD;
        float4 xr = *(const float4*)rp;
        float dtr = fmaf(xr.x, wv4.x, fmaf(xr.y, wv4.y, fmaf(xr.z, wv4.z, fmaf(xr.w, wv4.w, bias))));
        float dt = softplusf(dtr);
        Sdt += dt;
        int p = p_of(k, cc*TT + t);
        float u = xcb[(size_t)p*DI + d];
        float du = dt * u;
        float4 B0 = *(const float4*)(rp + 4);
        float4 B1 = *(const float4*)(rp + 8);
        float4 B2 = *(const float4*)(rp + 12);
        float4 B3 = *(const float4*)(rp + 16);
        float Bv[16] = {B0.x,B0.y,B0.z,B0.w, B1.x,B1.y,B1.z,B1.w,
                        B2.x,B2.y,B2.z,B2.w, B3.x,B3.y,B3.z,B3.w};
        #pragma unroll
        for (int i = 0; i < 16; i++){
            float e = __expf(dt * An[i]);
            h[i] = fmaf(h[i], e, du * Bv[i]);
        }
    }
    size_t ob = ((size_t)bid)*2048 + d*16;
    #pragma unroll
    for (int i = 0; i < 16; i++){
        Pbuf[ob + i] = __expf(An[i] * Sdt);
        Hbuf[ob + i] = h[i];
    }
}

// ---------------- K4b: chunk-boundary propagation hin_{c+1} = P_c*hin_c + H_c
__global__ __launch_bounds__(256) void k4b_prop(
    const float* __restrict__ Pbuf, const float* __restrict__ Hbuf,
    float* __restrict__ hin_buf)
{
    int chain = blockIdx.x*256 + threadIdx.x;   // 65536 chains
    int bk = chain >> 11, s = chain & 2047;
    float hin = 0.f;
    for (int c = 0; c < GG; c++){
        size_t idx = ((size_t)(bk*GG + c))*2048 + s;
        hin_buf[idx] = hin;
        hin = fmaf(Pbuf[idx], hin, Hbuf[idx]);
    }
}

// ---------------- K4c: per-chunk re-scan seeded with hin, emit y via atomics
__global__ __launch_bounds__(128, 4) void k4c_emit(
    const float* __restrict__ xc, const float* __restrict__ xdbl,
    const float* __restrict__ dtw, const float* __restrict__ dtb,
    const float* __restrict__ A_logs, const float* __restrict__ Ds,
    const float* __restrict__ hin_buf,
    float* __restrict__ y)
{
    int bid = blockIdx.x;
    int cc = bid & 63, k = (bid >> 6) & 3, b = bid >> 8;
    int d = threadIdx.x;
    int kd = k*DI + d;
    float4 wv4 = *(const float4*)(dtw + kd*4);
    float bias = dtb[kd];
    float Dv = Ds[kd];
    float An[16];
    {
        const float4* al = (const float4*)(A_logs + kd*16);
        #pragma unroll
        for (int i = 0; i < 4; i++){
            float4 a = al[i];
            An[i*4+0] = -__expf(a.x); An[i*4+1] = -__expf(a.y);
            An[i*4+2] = -__expf(a.z); An[i*4+3] = -__expf(a.w);
        }
    }
    __shared__ float sraw[TT*XD];
    const float* src = xdbl + ((size_t)(b*KK + k)*LL + cc*TT)*XD;
    for (int i = threadIdx.x; i < TT*XD/4; i += 128)
        ((float4*)sraw)[i] = ((const float4*)src)[i];
    __syncthreads();

    const float* xcb = xc + (size_t)b*LL*DI;
    float* yb = y + (size_t)b*LL*DI;
    float h[16];
    {
        const float4* hi = (const float4*)(hin_buf + ((size_t)bid)*2048 + d*16);
        #pragma unroll
        for (int i = 0; i < 4; i++){
            float4 a = hi[i];
            h[i*4+0] = a.x; h[i*4+1] = a.y; h[i*4+2] = a.z; h[i*4+3] = a.w;
        }
    }
    for (int t = 0; t < TT; t++){
        const float* rp = sraw + t*XD;
        float4 xr = *(const float4*)rp;
        float dtr = fmaf(xr.x, wv4.x, fmaf(xr.y, wv4.y, fmaf(xr.z, wv4.z, fmaf(xr.w, wv4.w, bias))));
        float dt = softplusf(dtr);
        int p = p_of(k, cc*TT + t);
        float u = xcb[(size_t)p*DI + d];
        float du = dt * u;
        float4 B0 = *(const float4*)(rp + 4);
        float4 B1 = *(const float4*)(rp + 8);
        float4 B2 = *(const float4*)(rp + 12);
        float4 B3 = *(const float4*)(rp + 16);
        float Bv[16] = {B0.x,B0.y,B0.z,B0.w, B1.x,B1.y,B1.z,B1.w,
                        B2.x,B2.y,B2.z,B2.w, B3.x,B3.y,B3.z,B3.w};
        float4 C0 = *(const float4*)(rp + 20);
        float4 C1 = *(const float4*)(rp + 24);
        float4 C2 = *(const float4*)(rp + 28);
        float4 C3 = *(const float4*)(rp + 32);
        float Cv[16] = {C0.x,C0.y,C0.z,C0.w, C1.x,C1.y,C1.z,C1.w,
                        C2.x,C2.y,C2.z,C2.w, C3.x,C3.y,C3.z,C3.w};
        float yv = Dv * u;
        #pragma unroll
        for (int i = 0; i < 16; i++){
            float e = __expf(dt * An[i]);
            h[i] = fmaf(h[i], e, du * Bv[i]);
            yv = fmaf(h[i], Cv[i], yv);
        }
        atomicAdd(&yb[(size_t)p*DI + d], yv);
    }
}

// ---------------- K4 serial fallback (round-3 version, used if ws too small)
__global__ __launch_bounds__(256) void k4_scan(
    const float* __restrict__ xc, const float* __restrict__ xdbl,
    const float* __restrict__ dtw, const float* __restrict__ dtb,
    const float* __restrict__ A_logs, const float* __restrict__ Ds,
    float* __restrict__ y)
{
    int bid = blockIdx.x;
    int b = bid >> 5, k = (bid >> 3) & 3, grp = bid & 7;
    int d0 = grp * 16;
    int tid = threadIdx.x;
    int wv = tid >> 6, lane = tid & 63, n = lane & 15, j = lane >> 4;
    int ch = wv*4 + j;
    int d = d0 + ch;
    int kd = k*DI + d;
    float An = -__expf(A_logs[kd*NN + n]);
    int ch_s = tid & 15;
    int kds = k*DI + d0 + ch_s;
    float w0s = dtw[kds*4+0], w1s = dtw[kds*4+1], w2s = dtw[kds*4+2], w3s = dtw[kds*4+3];
    float bs  = dtb[kds];
    float Dvs = Ds[kds];
    __shared__ float sraw[64*XD];
    __shared__ float sdd[64*16*2];
    __shared__ float sdy[64*17];
    const float* xdbase = xdbl + (size_t)(b*KK + k)*LL*XD;
    const float* xcb = xc + (size_t)b*LL*DI;
    float* yb = y + (size_t)b*LL*DI;
    float h = 0.f;
    for (int cc = 0; cc < 64; cc++){
        __syncthreads();
        const float* src = xdbase + (size_t)cc*64*XD;
        for (int i2 = tid; i2 < 576; i2 += 256)
            ((float4*)sraw)[i2] = ((const float4*)src)[i2];
        #pragma unroll
        for (int it = 0; it < 4; it++){
            int idx = tid + it*256;
            int t = idx >> 4;
            int pu = p_of(k, cc*64 + t);
            float u = xcb[(size_t)pu*DI + d0 + ch_s];
            float4 xr = *(const float4*)(src + t*XD);
            float dtr = fmaf(xr.x, w0s, fmaf(xr.y, w1s, fmaf(xr.z, w2s, fmaf(xr.w, w3s, bs))));
            float dt = softplusf(dtr);
            sdd[idx*2]     = dt;
            sdd[idx*2 + 1] = dt*u;
            sdy[t*17 + ch_s] = Dvs * u;
        }
        __syncthreads();
        #pragma unroll
        for (int tg = 0; tg < 4; tg++){
            float myv = 0.f;
            #pragma unroll
            for (int it = 0; it < 16; it++){
                int t = tg*16 + it;
                float dt = sdd[(t*16 + ch)*2];
                float du = sdd[(t*16 + ch)*2 + 1];
                float Bn = sraw[t*XD + 4 + n];
                float Cn = sraw[t*XD + 20 + n];
                float e = __expf(dt * An);
                h = fmaf(h, e, du * Bn);
                float yv = h * Cn;
                yv = dpp_xadd<0xB1>(yv);
                yv = dpp_xadd<0x4E>(yv);
                yv = dpp_xadd<0x141>(yv);
                yv = dpp_xadd<0x140>(yv);
                if (it == n) myv = yv;
            }
            int t = tg*16 + n;
            float yt = myv + sdy[t*17 + ch];
            int p = p_of(k, cc*64 + t);
            atomicAdd(&yb[(size_t)p*DI + d], yt);
        }
    }
}

// ---------------- K5: outnorm LN(DI) * silu(z) -> out_proj -> + residual -> xo (B,L,C)
__global__ __launch_bounds__(128) void k5_out(
    const float* __restrict__ y, const float* __restrict__ zs,
    const float* __restrict__ on_g, const float* __restrict__ on_b,
    const float* __restrict__ opw,  // (64,128)
    const float* __restrict__ opb,
    const float* __restrict__ x,    // (B,C,L)
    float* __restrict__ xo)
{
    int pid = blockIdx.x;
    int b = pid >> 12, p = pid & 4095;
    int d = threadIdx.x;
    __shared__ float v[128];
    __shared__ float red[4];
    size_t base = ((size_t)b*LL + p)*DI;
    float yv = y[base + d];
    float s = yv, q = yv*yv;
    #pragma unroll
    for (int off = 32; off; off >>= 1){ s += __shfl_xor(s, off, 64); q += __shfl_xor(q, off, 64); }
    if ((d & 63) == 0){ red[(d >> 6)*2] = s; red[(d >> 6)*2 + 1] = q; }
    __syncthreads();
    float mean = (red[0] + red[2]) * (1.f/128.f);
    float var  = (red[1] + red[3]) * (1.f/128.f) - mean*mean;
    float rstd = rsqrtf(var + 1e-5f);
    float yn = (yv - mean) * rstd * on_g[d] + on_b[d];
    v[d] = yn * zs[base + d];
    __syncthreads();
    if (d < 64){
        const float4* wr4 = (const float4*)(opw + d*DI);
        const float4* v4 = (const float4*)v;
        float acc = opb[d];
        #pragma unroll
        for (int i = 0; i < 32; i++){
            float4 a = v4[i], w = wr4[i];
            acc = fmaf(a.x, w.x, acc); acc = fmaf(a.y, w.y, acc);
            acc = fmaf(a.z, w.z, acc); acc = fmaf(a.w, w.w, acc);
        }
        acc += x[((size_t)(b*CC + d))*LL + p];
        xo[((size_t)b*LL + p)*CC + d] = acc;
    }
}

// ---------------- K6: channel LayerNorm over C -> cl (B,L,C)
__global__ __launch_bounds__(256) void k6_chln(
    const float* __restrict__ xo,
    const float* __restrict__ cn_g, const float* __restrict__ cn_b,
    float* __restrict__ cl)
{
    int pid = blockIdx.x*256 + threadIdx.x;
    if (pid >= BB*LL) return;
    const float4* r4 = (const float4*)(xo + (size_t)pid*CC);
    float s = 0.f, q = 0.f;
    #pragma unroll
    for (int i = 0; i < 16; i++){
        float4 a = r4[i];
        s += a.x + a.y + a.z + a.w;
        q = fmaf(a.x,a.x, fmaf(a.y,a.y, fmaf(a.z,a.z, fmaf(a.w,a.w, q))));
    }
    float mean = s * (1.f/64.f);
    float var  = q * (1.f/64.f) - mean*mean;
    float rstd = rsqrtf(var + 1e-6f);
    float4* o4 = (float4*)(cl + (size_t)pid*CC);
    const float4* g4 = (const float4*)cn_g;
    const float4* b4 = (const float4*)cn_b;
    #pragma unroll
    for (int i = 0; i < 16; i++){
        float4 a = r4[i], g = g4[i], bb = b4[i];
        float4 r;
        r.x = (a.x - mean)*rstd*g.x + bb.x;
        r.y = (a.y - mean)*rstd*g.y + bb.y;
        r.z = (a.z - mean)*rstd*g.z + bb.z;
        r.w = (a.w - mean)*rstd*g.w + bb.w;
        o4[i] = r;
    }
}

// ---------------- K7: max pools 2/4/8 for SAFM branches 1..3
__global__ __launch_bounds__(256) void k7_pools(const float* __restrict__ cl, float* __restrict__ pools)
{
    int idx = blockIdx.x*256 + threadIdx.x;
    int g, S, base;
    if (idx < 131072)      { g = 1; S = 32; base = 0; }
    else if (idx < 163840) { g = 2; S = 16; base = 131072; idx -= 131072; }
    else if (idx < 172032) { g = 3; S = 8;  base = 163840; idx -= 163840; }
    else return;
    int pw = idx % S; idx /= S;
    int ph = idx % S; idx /= S;
    int j = idx & 15; int b = idx >> 4;
    int kk = 64 / S;
    int c = g*16 + j;
    float m = -1e30f;
    for (int dy = 0; dy < kk; dy++)
        for (int dx = 0; dx < kk; dx++){
            int h = ph*kk + dy, w = pw*kk + dx;
            m = fmaxf(m, cl[((size_t)(b*LL) + h*64 + w)*CC + c]);
        }
    pools[base + ((size_t)(b*16 + j)*S + ph)*S + pw] = m;
}

// ---------------- K8: SAFM branch depthwise convs -> cat (B,L,C)
__global__ __launch_bounds__(256) void k8_mfr(
    const float* __restrict__ cl, const float* __restrict__ pools,
    const float* __restrict__ mfr_w,  // (4,16,3,3)
    const float* __restrict__ mfr_b,  // (4,16)
    float* __restrict__ cat)
{
    int idx = blockIdx.x*256 + threadIdx.x;   // (b*L+p)*64 + c
    int c = idx & 63; int bp = idx >> 6;
    int p = bp & 4095, b = bp >> 12;
    int g = c >> 4, j = c & 15;
    int h = p >> 6, w = p & 63;
    float acc = mfr_b[g*16 + j];
    const float* wr = mfr_w + (g*16 + j)*9;
    if (g == 0){
        #pragma unroll
        for (int ky = 0; ky < 3; ky++){
            int hh = h + ky - 1; if ((unsigned)hh >= 64u) continue;
            #pragma unroll
            for (int kx = 0; kx < 3; kx++){
                int ww = w + kx - 1; if ((unsigned)ww >= 64u) continue;
                acc = fmaf(cl[((size_t)(b*LL) + hh*64 + ww)*CC + c], wr[ky*3 + kx], acc);
            }
        }
    } else {
        int S = 64 >> g;
        int ph = h >> g, pw = w >> g;
        int base = (g == 1) ? 0 : ((g == 2) ? 131072 : 163840);
        const float* P = pools + base + (size_t)(b*16 + j)*S*S;
        #pragma unroll
        for (int ky = 0; ky < 3; ky++){
            int hh = ph + ky - 1; if ((unsigned)hh >= (unsigned)S) continue;
            #pragma unroll
            for (int kx = 0; kx < 3; kx++){
                int ww = pw + kx - 1; if ((unsigned)ww >= (unsigned)S) continue;
                acc = fmaf(P[hh*S + ww], wr[ky*3 + kx], acc);
            }
        }
    }
    cat[idx] = acc;
}

// ---------------- K9: 1x1 aggregation + GELU * cl + residual -> out (B,C,L) f32
__global__ __launch_bounds__(64) void k9_agg(
    const float* __restrict__ cat, const float* __restrict__ cl, const float* __restrict__ xo,
    const float* __restrict__ agw,   // (64,64)
    const float* __restrict__ agb,
    float* __restrict__ out)
{
    int pid = blockIdx.x;
    int b = pid >> 12, p = pid & 4095;
    int o = threadIdx.x;
    __shared__ float crow[64];
    size_t base = ((size_t)b*LL + p)*CC;
    crow[o] = cat[base + o];
    __syncthreads();
    const float4* wr4 = (const float4*)(agw + o*64);
    const float4* c4 = (const float4*)crow;
    float acc = agb[o];
    #pragma unroll
    for (int i = 0; i < 16; i++){
        float4 a = c4[i], w = wr4[i];
        acc = fmaf(a.x, w.x, acc); acc = fmaf(a.y, w.y, acc);
        acc = fmaf(a.z, w.z, acc); acc = fmaf(a.w, w.w, acc);
    }
    float gl = 0.5f*acc*(1.f + erff(acc*0.70710678118f));
    float res = xo[base + o] + gl*cl[base + o];
    out[((size_t)(b*CC + o))*LL + p] = res;
}

extern "C" void kernel_launch(void* const* d_in, const int* in_sizes, int n_in,
                              void* d_out, int out_size, void* d_ws, size_t ws_size,
                              hipStream_t stream)
{
    const float* x       = (const float*)d_in[0];
    const float* ln1_g   = (const float*)d_in[1];
    const float* ln1_b   = (const float*)d_in[2];
    const float* ipw     = (const float*)d_in[3];
    const float* ipb     = (const float*)d_in[4];
    const float* conv_w  = (const float*)d_in[5];
    const float* conv_b  = (const float*)d_in[6];
    const float* xpw     = (const float*)d_in[7];
    const float* dtw     = (const float*)d_in[8];
    const float* dtb     = (const float*)d_in[9];
    const float* A_logs  = (const float*)d_in[10];
    const float* Ds      = (const float*)d_in[11];
    const float* on_g    = (const float*)d_in[12];
    const float* on_b    = (const float*)d_in[13];
    const float* opw     = (const float*)d_in[14];
    const float* opb     = (const float*)d_in[15];
    const float* mfr_w   = (const float*)d_in[16];
    const float* mfr_b   = (const float*)d_in[17];
    const float* agw     = (const float*)d_in[18];
    const float* agb     = (const float*)d_in[19];
    const float* cn_g    = (const float*)d_in[20];
    const float* cn_b    = (const float*)d_in[21];
    float* out = (float*)d_out;

    float* ws = (float*)d_ws;
    float* xi    = ws;               // 4,194,304 ; reused as y
    float* zs    = ws + 4194304;     // 4,194,304 ; reused as cat
    float* xc    = ws + 8388608;     // 4,194,304 ; reused as xo + pools
    float* xdbl  = ws + 12582912;    // 4,718,592 ; reused as cl
    float* y     = xi;
    float* xo    = xc;
    float* pools = xc + 2097152;
    float* cl    = xdbl;
    float* cat   = zs;
    // parallel-scan scratch (beyond the base 17,301,504 floats)
    float* Pbuf  = ws + 17301504;    // 4,194,304
    float* Hbuf  = ws + 21495808;    // 4,194,304
    float* hinb  = ws + 25690112;    // 4,194,304
    bool par = ws_size >= (size_t)29884416 * 4;

    // SS2D
    hipLaunchKernelGGL(k1_ln_inproj, dim3(BB*LL), dim3(256), 0, stream,
                       x, ln1_g, ln1_b, ipw, ipb, xi, zs);
    hipLaunchKernelGGL(k2_dwconv, dim3(BB*LL*DI/256), dim3(256), 0, stream,
                       xi, conv_w, conv_b, xc);
    hipLaunchKernelGGL(k3_xdbl, dim3(BB*LL), dim3(64), 0, stream,
                       xc, xpw, xdbl);
    hipMemsetAsync(y, 0, (size_t)BB*LL*DI*sizeof(float), stream);
    if (par){
        hipLaunchKernelGGL(k4a_local, dim3(BB*KK*GG), dim3(128), 0, stream,
                           xc, xdbl, dtw, dtb, A_logs, Pbuf, Hbuf);
        hipLaunchKernelGGL(k4b_prop, dim3(256), dim3(256), 0, stream,
                           Pbuf, Hbuf, hinb);
        hipLaunchKernelGGL(k4c_emit, dim3(BB*KK*GG), dim3(128), 0, stream,
                           xc, xdbl, dtw, dtb, A_logs, Ds, hinb, y);
    } else {
        hipLaunchKernelGGL(k4_scan, dim3(256), dim3(256), 0, stream,
                           xc, xdbl, dtw, dtb, A_logs, Ds, y);
    }
    hipLaunchKernelGGL(k5_out, dim3(BB*LL), dim3(128), 0, stream,
                       y, zs, on_g, on_b, opw, opb, x, xo);
    // SAFM
    hipLaunchKernelGGL(k6_chln, dim3((BB*LL + 255)/256), dim3(256), 0, stream,
                       xo, cn_g, cn_b, cl);
    hipLaunchKernelGGL(k7_pools, dim3((172032 + 255)/256), dim3(256), 0, stream,
                       cl, pools);
    hipLaunchKernelGGL(k8_mfr, dim3(BB*LL*CC/256), dim3(256), 0, stream,
                       cl, pools, mfr_w, mfr_b, cat);
    hipLaunchKernelGGL(k9_agg, dim3(BB*LL), dim3(64), 0, stream,
                       cat, cl, xo, agw, agb, out);
}

// Round 5
// 806.724 us; speedup vs baseline: 3.8578x; 1.3240x over previous
//
#include <hip/hip_runtime.h>
#include <hip/hip_bf16.h>

#define BB 8
#define CC 64
#define HH 64
#define WW 64
#define LL 4096
#define DI 128
#define KK 4
#define NN 16
#define RR 4
#define XD 36   // R + 2N
#define GG 64   // scan chunks
#define TT 64   // timesteps per chunk

__device__ __forceinline__ float softplusf(float x){
    // stable: max(x,0) + log(1+exp(-|x|))
    return fmaxf(x, 0.f) + __logf(1.f + __expf(-fabsf(x)));
}
__device__ __forceinline__ int p_of(int k, int t){
    int tt = (k & 2) ? (LL - 1 - t) : t;
    return (k & 1) ? ((tt & 63) * 64 + (tt >> 6)) : tt;
}

// DPP butterfly add over the 16-lane row (serial fallback kernel only)
template<int CTRL>
__device__ __forceinline__ float dpp_xadd(float v){
    int t = __builtin_amdgcn_update_dpp(0, __float_as_int(v), CTRL, 0xF, 0xF, true);
    return v + __int_as_float(t);
}

// ---------------- K1: LayerNorm(C) + in_proj -> xi (B,L,DI), zs=silu(z) (B,L,DI)
__global__ __launch_bounds__(256) void k1_ln_inproj(
    const float* __restrict__ x,     // (B,C,L)
    const float* __restrict__ ln1_g,
    const float* __restrict__ ln1_b,
    const float* __restrict__ ipw,   // (256,64)
    const float* __restrict__ ipb,   // (256)
    float* __restrict__ xi, float* __restrict__ zs)
{
    int pid = blockIdx.x;
    int b = pid >> 12, p = pid & 4095;
    __shared__ float lnx[64];
    int tid = threadIdx.x;
    if (tid < 64) {
        float v = x[((size_t)(b*CC + tid))*LL + p];
        float s = v, q = v*v;
        #pragma unroll
        for (int off = 32; off; off >>= 1){ s += __shfl_xor(s, off, 64); q += __shfl_xor(q, off, 64); }
        float mean = s * (1.0f/64.0f);
        float var  = q * (1.0f/64.0f) - mean*mean;
        float rstd = rsqrtf(var + 1e-5f);
        lnx[tid] = (v - mean) * rstd * ln1_g[tid] + ln1_b[tid];
    }
    __syncthreads();
    int d = tid;
    const float4* wr4 = (const float4*)(ipw + d*64);
    const float4* ln4 = (const float4*)lnx;
    float a0 = 0.f, a1 = 0.f, a2 = 0.f, a3 = 0.f;
    #pragma unroll
    for (int i = 0; i < 16; i++){
        float4 a = ln4[i], w = wr4[i];
        a0 = fmaf(a.x, w.x, a0); a1 = fmaf(a.y, w.y, a1);
        a2 = fmaf(a.z, w.z, a2); a3 = fmaf(a.w, w.w, a3);
    }
    float acc = (a0 + a1) + (a2 + a3) + ipb[d];
    size_t base = ((size_t)b*LL + p)*DI;
    if (d < DI) {
        xi[base + d] = acc;
    } else {
        float sg = 1.f / (1.f + __expf(-acc));
        zs[base + d - DI] = acc * sg;
    }
}

// ---------------- K2: depthwise 3x3 + SiLU -> xc (B,L,DI)
__global__ __launch_bounds__(256) void k2_dwconv(
    const float* __restrict__ xi,
    const float* __restrict__ cw,   // (128,3,3)
    const float* __restrict__ cb,
    float* __restrict__ xc)
{
    int idx = blockIdx.x*256 + threadIdx.x;   // (b*L+p)*128 + d
    int d = idx & 127;
    int bp = idx >> 7;
    int p = bp & 4095, b = bp >> 12;
    int h = p >> 6, w = p & 63;
    float acc = cb[d];
    #pragma unroll
    for (int ky = 0; ky < 3; ky++){
        int hh = h + ky - 1;
        if ((unsigned)hh >= 64u) continue;
        #pragma unroll
        for (int kx = 0; kx < 3; kx++){
            int ww = w + kx - 1;
            if ((unsigned)ww >= 64u) continue;
            acc = fmaf(xi[((size_t)(b*LL) + hh*64 + ww)*DI + d], cw[d*9 + ky*3 + kx], acc);
        }
    }
    float sg = 1.f / (1.f + __expf(-acc));
    xc[idx] = acc * sg;
}

// ---------------- K3: x_dbl = xproj(xc), register-tiled LDS GEMM
// block = 64 pixels, 256 threads = 16 out-tiles (9 outputs) x 16 pix-tiles (4 pixels)
__global__ __launch_bounds__(256) void k3_xdbl(
    const float* __restrict__ xc,
    const float* __restrict__ xpw,   // (144,128) row-major
    float* __restrict__ xdbl)
{
    int bid = blockIdx.x;            // b*64 + ptile
    int b = bid >> 6, ptile = bid & 63;
    int tid = threadIdx.x;
    int ot = tid & 15;               // out-tile: outputs ot*9 .. ot*9+8
    int pt = tid >> 4;               // pix-tile: pixels pt*4 .. pt*4+3

    __shared__ float r[64*132];      // 64 pixel rows, padded stride 132
    __shared__ float wT[32*192];     // per-chunk weights, wT[k][ot*12+j]

    const float* xcb = xc + ((size_t)(b*LL) + ptile*64)*DI;
    for (int i = tid; i < 2048; i += 256){
        int pix = i >> 5, kq = i & 31;
        float4 v = *(const float4*)(xcb + pix*128 + kq*4);
        *(float4*)(r + pix*132 + kq*4) = v;
    }

    float acc[9][4];
    #pragma unroll
    for (int j = 0; j < 9; j++)
        #pragma unroll
        for (int i2 = 0; i2 < 4; i2++) acc[j][i2] = 0.f;

    for (int kc = 0; kc < 4; kc++){
        __syncthreads();             // wT of prev chunk fully consumed (r ready on kc=0)
        int k0 = kc*32;
        for (int i = tid; i < 1152; i += 256){
            int cl = i >> 3, jq = i & 7;        // cl = k*36+c (0..143), jq = f4 within 32 k
            float4 wv = *(const float4*)(xpw + cl*128 + k0 + jq*4);
            int o = (cl*456) >> 12;             // cl / 9
            int j = cl - o*9;
            wT[(jq*4+0)*192 + o*12 + j] = wv.x;
            wT[(jq*4+1)*192 + o*12 + j] = wv.y;
            wT[(jq*4+2)*192 + o*12 + j] = wv.z;
            wT[(jq*4+3)*192 + o*12 + j] = wv.w;
        }
        __syncthreads();
        const float* rbase = r + (pt*4)*132 + k0;
        #pragma unroll 4
        for (int k = 0; k < 32; k++){
            float4 wa = *(const float4*)(wT + k*192 + ot*12);
            float4 wb = *(const float4*)(wT + k*192 + ot*12 + 4);
            float w8 = wT[k*192 + ot*12 + 8];
            float rv0 = rbase[k];
            float rv1 = rbase[132 + k];
            float rv2 = rbase[264 + k];
            float rv3 = rbase[396 + k];
            float wv[9] = {wa.x, wa.y, wa.z, wa.w, wb.x, wb.y, wb.z, wb.w, w8};
            float rv[4] = {rv0, rv1, rv2, rv3};
            #pragma unroll
            for (int j = 0; j < 9; j++)
                #pragma unroll
                for (int i2 = 0; i2 < 4; i2++)
                    acc[j][i2] = fmaf(wv[j], rv[i2], acc[j][i2]);
        }
    }

    // epilogue: scatter to sequence order
    int kd = ot >> 2;                 // direction
    int cbase = (ot & 3)*9;           // channel within direction
    size_t obase = ((size_t)(b*KK + kd))*LL;
    #pragma unroll
    for (int i2 = 0; i2 < 4; i2++){
        int p = ptile*64 + pt*4 + i2;
        int tT = (p & 63)*64 + (p >> 6);
        int t = (kd == 0) ? p : (kd == 1) ? tT : (kd == 2) ? (4095 - p) : (4095 - tT);
        float* dst = xdbl + (obase + t)*XD + cbase;
        #pragma unroll
        for (int j = 0; j < 9; j++) dst[j] = acc[j][i2];
    }
}

// ---------------- K4a: per-chunk local scan -> H (local final h), P (chunk decay)
__global__ __launch_bounds__(128, 4) void k4a_local(
    const float* __restrict__ xc, const float* __restrict__ xdbl,
    const float* __restrict__ dtw, const float* __restrict__ dtb,
    const float* __restrict__ A_logs,
    float* __restrict__ Pbuf, float* __restrict__ Hbuf)
{
    int bid = blockIdx.x;            // ((b*4+k)*64+cc)
    int cc = bid & 63, k = (bid >> 6) & 3, b = bid >> 8;
    int d = threadIdx.x;
    int kd = k*DI + d;
    float4 wv4 = *(const float4*)(dtw + kd*4);
    float bias = dtb[kd];
    float An[16];
    {
        const float4* al = (const float4*)(A_logs + kd*16);
        #pragma unroll
        for (int i = 0; i < 4; i++){
            float4 a = al[i];
            An[i*4+0] = -__expf(a.x); An[i*4+1] = -__expf(a.y);
            An[i*4+2] = -__expf(a.z); An[i*4+3] = -__expf(a.w);
        }
    }
    __shared__ float sraw[TT*XD];
    const float* src = xdbl + ((size_t)(b*KK + k)*LL + cc*TT)*XD;
    for (int i = threadIdx.x; i < TT*XD/4; i += 128)
        ((float4*)sraw)[i] = ((const float4*)src)[i];
    __syncthreads();

    const float* xcb = xc + (size_t)b*LL*DI;
    float h[16];
    #pragma unroll
    for (int i = 0; i < 16; i++) h[i] = 0.f;
    float Sdt = 0.f;
    for (int t = 0; t < TT; t++){
        const float* rp = sraw + t*XD;
        float4 xr = *(const float4*)rp;
        float dtr = fmaf(xr.x, wv4.x, fmaf(xr.y, wv4.y, fmaf(xr.z, wv4.z, fmaf(xr.w, wv4.w, bias))));
        float dt = softplusf(dtr);
        Sdt += dt;
        int p = p_of(k, cc*TT + t);
        float u = xcb[(size_t)p*DI + d];
        float du = dt * u;
        float4 B0 = *(const float4*)(rp + 4);
        float4 B1 = *(const float4*)(rp + 8);
        float4 B2 = *(const float4*)(rp + 12);
        float4 B3 = *(const float4*)(rp + 16);
        float Bv[16] = {B0.x,B0.y,B0.z,B0.w, B1.x,B1.y,B1.z,B1.w,
                        B2.x,B2.y,B2.z,B2.w, B3.x,B3.y,B3.z,B3.w};
        #pragma unroll
        for (int i = 0; i < 16; i++){
            float e = __expf(dt * An[i]);
            h[i] = fmaf(h[i], e, du * Bv[i]);
        }
    }
    size_t ob = ((size_t)bid)*2048 + d*16;
    #pragma unroll
    for (int i = 0; i < 16; i++){
        Pbuf[ob + i] = __expf(An[i] * Sdt);
        Hbuf[ob + i] = h[i];
    }
}

// ---------------- K4b: chunk-boundary propagation hin_{c+1} = P_c*hin_c + H_c
__global__ __launch_bounds__(256) void k4b_prop(
    const float* __restrict__ Pbuf, const float* __restrict__ Hbuf,
    float* __restrict__ hin_buf)
{
    int chain = blockIdx.x*256 + threadIdx.x;   // 65536 chains
    int bk = chain >> 11, s = chain & 2047;
    float hin = 0.f;
    for (int c = 0; c < GG; c++){
        size_t idx = ((size_t)(bk*GG + c))*2048 + s;
        hin_buf[idx] = hin;
        hin = fmaf(Pbuf[idx], hin, Hbuf[idx]);
    }
}

// ---------------- K4c: per-chunk re-scan seeded with hin, emit y via atomics
__global__ __launch_bounds__(128, 4) void k4c_emit(
    const float* __restrict__ xc, const float* __restrict__ xdbl,
    const float* __restrict__ dtw, const float* __restrict__ dtb,
    const float* __restrict__ A_logs, const float* __restrict__ Ds,
    const float* __restrict__ hin_buf,
    float* __restrict__ y)
{
    int bid = blockIdx.x;
    int cc = bid & 63, k = (bid >> 6) & 3, b = bid >> 8;
    int d = threadIdx.x;
    int kd = k*DI + d;
    float4 wv4 = *(const float4*)(dtw + kd*4);
    float bias = dtb[kd];
    float Dv = Ds[kd];
    float An[16];
    {
        const float4* al = (const float4*)(A_logs + kd*16);
        #pragma unroll
        for (int i = 0; i < 4; i++){
            float4 a = al[i];
            An[i*4+0] = -__expf(a.x); An[i*4+1] = -__expf(a.y);
            An[i*4+2] = -__expf(a.z); An[i*4+3] = -__expf(a.w);
        }
    }
    __shared__ float sraw[TT*XD];
    const float* src = xdbl + ((size_t)(b*KK + k)*LL + cc*TT)*XD;
    for (int i = threadIdx.x; i < TT*XD/4; i += 128)
        ((float4*)sraw)[i] = ((const float4*)src)[i];
    __syncthreads();

    const float* xcb = xc + (size_t)b*LL*DI;
    float* yb = y + (size_t)b*LL*DI;
    float h[16];
    {
        const float4* hi = (const float4*)(hin_buf + ((size_t)bid)*2048 + d*16);
        #pragma unroll
        for (int i = 0; i < 4; i++){
            float4 a = hi[i];
            h[i*4+0] = a.x; h[i*4+1] = a.y; h[i*4+2] = a.z; h[i*4+3] = a.w;
        }
    }
    for (int t = 0; t < TT; t++){
        const float* rp = sraw + t*XD;
        float4 xr = *(const float4*)rp;
        float dtr = fmaf(xr.x, wv4.x, fmaf(xr.y, wv4.y, fmaf(xr.z, wv4.z, fmaf(xr.w, wv4.w, bias))));
        float dt = softplusf(dtr);
        int p = p_of(k, cc*TT + t);
        float u = xcb[(size_t)p*DI + d];
        float du = dt * u;
        float4 B0 = *(const float4*)(rp + 4);
        float4 B1 = *(const float4*)(rp + 8);
        float4 B2 = *(const float4*)(rp + 12);
        float4 B3 = *(const float4*)(rp + 16);
        float Bv[16] = {B0.x,B0.y,B0.z,B0.w, B1.x,B1.y,B1.z,B1.w,
                        B2.x,B2.y,B2.z,B2.w, B3.x,B3.y,B3.z,B3.w};
        float4 C0 = *(const float4*)(rp + 20);
        float4 C1 = *(const float4*)(rp + 24);
        float4 C2 = *(const float4*)(rp + 28);
        float4 C3 = *(const float4*)(rp + 32);
        float Cv[16] = {C0.x,C0.y,C0.z,C0.w, C1.x,C1.y,C1.z,C1.w,
                        C2.x,C2.y,C2.z,C2.w, C3.x,C3.y,C3.z,C3.w};
        float yv = Dv * u;
        #pragma unroll
        for (int i = 0; i < 16; i++){
            float e = __expf(dt * An[i]);
            h[i] = fmaf(h[i], e, du * Bv[i]);
            yv = fmaf(h[i], Cv[i], yv);
        }
        atomicAdd(&yb[(size_t)p*DI + d], yv);
    }
}

// ---------------- K4 serial fallback (used if ws too small)
__global__ __launch_bounds__(256) void k4_scan(
    const float* __restrict__ xc, const float* __restrict__ xdbl,
    const float* __restrict__ dtw, const float* __restrict__ dtb,
    const float* __restrict__ A_logs, const float* __restrict__ Ds,
    float* __restrict__ y)
{
    int bid = blockIdx.x;
    int b = bid >> 5, k = (bid >> 3) & 3, grp = bid & 7;
    int d0 = grp * 16;
    int tid = threadIdx.x;
    int wv = tid >> 6, lane = tid & 63, n = lane & 15, j = lane >> 4;
    int ch = wv*4 + j;
    int d = d0 + ch;
    int kd = k*DI + d;
    float An = -__expf(A_logs[kd*NN + n]);
    int ch_s = tid & 15;
    int kds = k*DI + d0 + ch_s;
    float w0s = dtw[kds*4+0], w1s = dtw[kds*4+1], w2s = dtw[kds*4+2], w3s = dtw[kds*4+3];
    float bs  = dtb[kds];
    float Dvs = Ds[kds];
    __shared__ float sraw[64*XD];
    __shared__ float sdd[64*16*2];
    __shared__ float sdy[64*17];
    const float* xdbase = xdbl + (size_t)(b*KK + k)*LL*XD;
    const float* xcb = xc + (size_t)b*LL*DI;
    float* yb = y + (size_t)b*LL*DI;
    float h = 0.f;
    for (int cc = 0; cc < 64; cc++){
        __syncthreads();
        const float* src = xdbase + (size_t)cc*64*XD;
        for (int i2 = tid; i2 < 576; i2 += 256)
            ((float4*)sraw)[i2] = ((const float4*)src)[i2];
        #pragma unroll
        for (int it = 0; it < 4; it++){
            int idx = tid + it*256;
            int t = idx >> 4;
            int pu = p_of(k, cc*64 + t);
            float u = xcb[(size_t)pu*DI + d0 + ch_s];
            float4 xr = *(const float4*)(src + t*XD);
            float dtr = fmaf(xr.x, w0s, fmaf(xr.y, w1s, fmaf(xr.z, w2s, fmaf(xr.w, w3s, bs))));
            float dt = softplusf(dtr);
            sdd[idx*2]     = dt;
            sdd[idx*2 + 1] = dt*u;
            sdy[t*17 + ch_s] = Dvs * u;
        }
        __syncthreads();
        #pragma unroll
        for (int tg = 0; tg < 4; tg++){
            float myv = 0.f;
            #pragma unroll
            for (int it = 0; it < 16; it++){
                int t = tg*16 + it;
                float dt = sdd[(t*16 + ch)*2];
                float du = sdd[(t*16 + ch)*2 + 1];
                float Bn = sraw[t*XD + 4 + n];
                float Cn = sraw[t*XD + 20 + n];
                float e = __expf(dt * An);
                h = fmaf(h, e, du * Bn);
                float yv = h * Cn;
                yv = dpp_xadd<0xB1>(yv);
                yv = dpp_xadd<0x4E>(yv);
                yv = dpp_xadd<0x141>(yv);
                yv = dpp_xadd<0x140>(yv);
                if (it == n) myv = yv;
            }
            int t = tg*16 + n;
            float yt = myv + sdy[t*17 + ch];
            int p = p_of(k, cc*64 + t);
            atomicAdd(&yb[(size_t)p*DI + d], yt);
        }
    }
}

// ---------------- K5: outnorm LN(DI) * silu(z) -> out_proj -> + residual -> xo (B,L,C)
__global__ __launch_bounds__(128) void k5_out(
    const float* __restrict__ y, const float* __restrict__ zs,
    const float* __restrict__ on_g, const float* __restrict__ on_b,
    const float* __restrict__ opw,  // (64,128)
    const float* __restrict__ opb,
    const float* __restrict__ x,    // (B,C,L)
    float* __restrict__ xo)
{
    int pid = blockIdx.x;
    int b = pid >> 12, p = pid & 4095;
    int d = threadIdx.x;
    __shared__ float v[128];
    __shared__ float red[4];
    size_t base = ((size_t)b*LL + p)*DI;
    float yv = y[base + d];
    float s = yv, q = yv*yv;
    #pragma unroll
    for (int off = 32; off; off >>= 1){ s += __shfl_xor(s, off, 64); q += __shfl_xor(q, off, 64); }
    if ((d & 63) == 0){ red[(d >> 6)*2] = s; red[(d >> 6)*2 + 1] = q; }
    __syncthreads();
    float mean = (red[0] + red[2]) * (1.f/128.f);
    float var  = (red[1] + red[3]) * (1.f/128.f) - mean*mean;
    float rstd = rsqrtf(var + 1e-5f);
    float yn = (yv - mean) * rstd * on_g[d] + on_b[d];
    v[d] = yn * zs[base + d];
    __syncthreads();
    if (d < 64){
        const float4* wr4 = (const float4*)(opw + d*DI);
        const float4* v4 = (const float4*)v;
        float a0 = 0.f, a1 = 0.f, a2 = 0.f, a3 = 0.f;
        #pragma unroll
        for (int i = 0; i < 32; i++){
            float4 a = v4[i], w = wr4[i];
            a0 = fmaf(a.x, w.x, a0); a1 = fmaf(a.y, w.y, a1);
            a2 = fmaf(a.z, w.z, a2); a3 = fmaf(a.w, w.w, a3);
        }
        float acc = (a0 + a1) + (a2 + a3) + opb[d];
        acc += x[((size_t)(b*CC + d))*LL + p];
        xo[((size_t)b*LL + p)*CC + d] = acc;
    }
}

// ---------------- K6: channel LayerNorm over C -> cl (B,L,C)
__global__ __launch_bounds__(256) void k6_chln(
    const float* __restrict__ xo,
    const float* __restrict__ cn_g, const float* __restrict__ cn_b,
    float* __restrict__ cl)
{
    int pid = blockIdx.x*256 + threadIdx.x;
    if (pid >= BB*LL) return;
    const float4* r4 = (const float4*)(xo + (size_t)pid*CC);
    float s = 0.f, q = 0.f;
    #pragma unroll
    for (int i = 0; i < 16; i++){
        float4 a = r4[i];
        s += a.x + a.y + a.z + a.w;
        q = fmaf(a.x,a.x, fmaf(a.y,a.y, fmaf(a.z,a.z, fmaf(a.w,a.w, q))));
    }
    float mean = s * (1.f/64.f);
    float var  = q * (1.f/64.f) - mean*mean;
    float rstd = rsqrtf(var + 1e-6f);
    float4* o4 = (float4*)(cl + (size_t)pid*CC);
    const float4* g4 = (const float4*)cn_g;
    const float4* b4 = (const float4*)cn_b;
    #pragma unroll
    for (int i = 0; i < 16; i++){
        float4 a = r4[i], g = g4[i], bb = b4[i];
        float4 r;
        r.x = (a.x - mean)*rstd*g.x + bb.x;
        r.y = (a.y - mean)*rstd*g.y + bb.y;
        r.z = (a.z - mean)*rstd*g.z + bb.z;
        r.w = (a.w - mean)*rstd*g.w + bb.w;
        o4[i] = r;
    }
}

// ---------------- K7: max pools 2/4/8 for SAFM branches 1..3
__global__ __launch_bounds__(256) void k7_pools(const float* __restrict__ cl, float* __restrict__ pools)
{
    int idx = blockIdx.x*256 + threadIdx.x;
    int g, S, base;
    if (idx < 131072)      { g = 1; S = 32; base = 0; }
    else if (idx < 163840) { g = 2; S = 16; base = 131072; idx -= 131072; }
    else if (idx < 172032) { g = 3; S = 8;  base = 163840; idx -= 163840; }
    else return;
    int pw = idx % S; idx /= S;
    int ph = idx % S; idx /= S;
    int j = idx & 15; int b = idx >> 4;
    int kk = 64 / S;
    int c = g*16 + j;
    float m = -1e30f;
    for (int dy = 0; dy < kk; dy++)
        for (int dx = 0; dx < kk; dx++){
            int h = ph*kk + dy, w = pw*kk + dx;
            m = fmaxf(m, cl[((size_t)(b*LL) + h*64 + w)*CC + c]);
        }
    pools[base + ((size_t)(b*16 + j)*S + ph)*S + pw] = m;
}

// ---------------- K8: SAFM branch depthwise convs -> cat (B,L,C)
__global__ __launch_bounds__(256) void k8_mfr(
    const float* __restrict__ cl, const float* __restrict__ pools,
    const float* __restrict__ mfr_w,  // (4,16,3,3)
    const float* __restrict__ mfr_b,  // (4,16)
    float* __restrict__ cat)
{
    int idx = blockIdx.x*256 + threadIdx.x;   // (b*L+p)*64 + c
    int c = idx & 63; int bp = idx >> 6;
    int p = bp & 4095, b = bp >> 12;
    int g = c >> 4, j = c & 15;
    int h = p >> 6, w = p & 63;
    float acc = mfr_b[g*16 + j];
    const float* wr = mfr_w + (g*16 + j)*9;
    if (g == 0){
        #pragma unroll
        for (int ky = 0; ky < 3; ky++){
            int hh = h + ky - 1; if ((unsigned)hh >= 64u) continue;
            #pragma unroll
            for (int kx = 0; kx < 3; kx++){
                int ww = w + kx - 1; if ((unsigned)ww >= 64u) continue;
                acc = fmaf(cl[((size_t)(b*LL) + hh*64 + ww)*CC + c], wr[ky*3 + kx], acc);
            }
        }
    } else {
        int S = 64 >> g;
        int ph = h >> g, pw = w >> g;
        int base = (g == 1) ? 0 : ((g == 2) ? 131072 : 163840);
        const float* P = pools + base + (size_t)(b*16 + j)*S*S;
        #pragma unroll
        for (int ky = 0; ky < 3; ky++){
            int hh = ph + ky - 1; if ((unsigned)hh >= (unsigned)S) continue;
            #pragma unroll
            for (int kx = 0; kx < 3; kx++){
                int ww = pw + kx - 1; if ((unsigned)ww >= (unsigned)S) continue;
                acc = fmaf(P[hh*S + ww], wr[ky*3 + kx], acc);
            }
        }
    }
    cat[idx] = acc;
}

// ---------------- K9: 1x1 aggregation + GELU * cl + residual -> out (B,C,L) f32
__global__ __launch_bounds__(64) void k9_agg(
    const float* __restrict__ cat, const float* __restrict__ cl, const float* __restrict__ xo,
    const float* __restrict__ agw,   // (64,64)
    const float* __restrict__ agb,
    float* __restrict__ out)
{
    int pid = blockIdx.x;
    int b = pid >> 12, p = pid & 4095;
    int o = threadIdx.x;
    __shared__ float crow[64];
    size_t base = ((size_t)b*LL + p)*CC;
    crow[o] = cat[base + o];
    __syncthreads();
    const float4* wr4 = (const float4*)(agw + o*64);
    const float4* c4 = (const float4*)crow;
    float a0 = 0.f, a1 = 0.f, a2 = 0.f, a3 = 0.f;
    #pragma unroll
    for (int i = 0; i < 16; i++){
        float4 a = c4[i], w = wr4[i];
        a0 = fmaf(a.x, w.x, a0); a1 = fmaf(a.y, w.y, a1);
        a2 = fmaf(a.z, w.z, a2); a3 = fmaf(a.w, w.w, a3);
    }
    float acc = (a0 + a1) + (a2 + a3) + agb[o];
    float gl = 0.5f*acc*(1.f + erff(acc*0.70710678118f));
    float res = xo[base + o] + gl*cl[base + o];
    out[((size_t)(b*CC + o))*LL + p] = res;
}

extern "C" void kernel_launch(void* const* d_in, const int* in_sizes, int n_in,
                              void* d_out, int out_size, void* d_ws, size_t ws_size,
                              hipStream_t stream)
{
    const float* x       = (const float*)d_in[0];
    const float* ln1_g   = (const float*)d_in[1];
    const float* ln1_b   = (const float*)d_in[2];
    const float* ipw     = (const float*)d_in[3];
    const float* ipb     = (const float*)d_in[4];
    const float* conv_w  = (const float*)d_in[5];
    const float* conv_b  = (const float*)d_in[6];
    const float* xpw     = (const float*)d_in[7];
    const float* dtw     = (const float*)d_in[8];
    const float* dtb     = (const float*)d_in[9];
    const float* A_logs  = (const float*)d_in[10];
    const float* Ds      = (const float*)d_in[11];
    const float* on_g    = (const float*)d_in[12];
    const float* on_b    = (const float*)d_in[13];
    const float* opw     = (const float*)d_in[14];
    const float* opb     = (const float*)d_in[15];
    const float* mfr_w   = (const float*)d_in[16];
    const float* mfr_b   = (const float*)d_in[17];
    const float* agw     = (const float*)d_in[18];
    const float* agb     = (const float*)d_in[19];
    const float* cn_g    = (const float*)d_in[20];
    const float* cn_b    = (const float*)d_in[21];
    float* out = (float*)d_out;

    float* ws = (float*)d_ws;
    float* xi    = ws;               // 4,194,304 ; reused as y
    float* zs    = ws + 4194304;     // 4,194,304 ; reused as cat
    float* xc    = ws + 8388608;     // 4,194,304 ; reused as xo + pools
    float* xdbl  = ws + 12582912;    // 4,718,592 ; reused as cl
    float* y     = xi;
    float* xo    = xc;
    float* pools = xc + 2097152;
    float* cl    = xdbl;
    float* cat   = zs;
    // parallel-scan scratch (beyond the base 17,301,504 floats)
    float* Pbuf  = ws + 17301504;    // 4,194,304
    float* Hbuf  = ws + 21495808;    // 4,194,304
    float* hinb  = ws + 25690112;    // 4,194,304
    bool par = ws_size >= (size_t)29884416 * 4;

    // SS2D
    hipLaunchKernelGGL(k1_ln_inproj, dim3(BB*LL), dim3(256), 0, stream,
                       x, ln1_g, ln1_b, ipw, ipb, xi, zs);
    hipLaunchKernelGGL(k2_dwconv, dim3(BB*LL*DI/256), dim3(256), 0, stream,
                       xi, conv_w, conv_b, xc);
    hipLaunchKernelGGL(k3_xdbl, dim3(BB*64), dim3(256), 0, stream,
                       xc, xpw, xdbl);
    hipMemsetAsync(y, 0, (size_t)BB*LL*DI*sizeof(float), stream);
    if (par){
        hipLaunchKernelGGL(k4a_local, dim3(BB*KK*GG), dim3(128), 0, stream,
                           xc, xdbl, dtw, dtb, A_logs, Pbuf, Hbuf);
        hipLaunchKernelGGL(k4b_prop, dim3(256), dim3(256), 0, stream,
                           Pbuf, Hbuf, hinb);
        hipLaunchKernelGGL(k4c_emit, dim3(BB*KK*GG), dim3(128), 0, stream,
                           xc, xdbl, dtw, dtb, A_logs, Ds, hinb, y);
    } else {
        hipLaunchKernelGGL(k4_scan, dim3(256), dim3(256), 0, stream,
                           xc, xdbl, dtw, dtb, A_logs, Ds, y);
    }
    hipLaunchKernelGGL(k5_out, dim3(BB*LL), dim3(128), 0, stream,
                       y, zs, on_g, on_b, opw, opb, x, xo);
    // SAFM
    hipLaunchKernelGGL(k6_chln, dim3((BB*LL + 255)/256), dim3(256), 0, stream,
                       xo, cn_g, cn_b, cl);
    hipLaunchKernelGGL(k7_pools, dim3((172032 + 255)/256), dim3(256), 0, stream,
                       cl, pools);
    hipLaunchKernelGGL(k8_mfr, dim3(BB*LL*CC/256), dim3(256), 0, stream,
                       cl, pools, mfr_w, mfr_b, cat);
    hipLaunchKernelGGL(k9_agg, dim3(BB*LL), dim3(64), 0, stream,
                       cat, cl, xo, agw, agb, out);
}

// Round 6
// 423.550 us; speedup vs baseline: 7.3478x; 1.9047x over previous
//
#include <hip/hip_runtime.h>
#include <hip/hip_bf16.h>

#define BB 8
#define CC 64
#define HH 64
#define WW 64
#define LL 4096
#define DI 128
#define KK 4
#define NN 16
#define RR 4
#define XD 36   // R + 2N
#define GG 64   // scan chunks
#define TT 64   // timesteps per chunk

__device__ __forceinline__ float softplusf(float x){
    return fmaxf(x, 0.f) + __logf(1.f + __expf(-fabsf(x)));
}
__device__ __forceinline__ int p_of(int k, int t){
    int tt = (k & 2) ? (LL - 1 - t) : t;
    return (k & 1) ? ((tt & 63) * 64 + (tt >> 6)) : tt;
}

// DPP butterfly add (serial fallback kernel only)
template<int CTRL>
__device__ __forceinline__ float dpp_xadd(float v){
    int t = __builtin_amdgcn_update_dpp(0, __float_as_int(v), CTRL, 0xF, 0xF, true);
    return v + __int_as_float(t);
}

// ---------------- K1: LN(C) + in_proj, 64-pixel-tile LDS GEMM
// block = 64 pixels; 256 thr = 16 pix-tiles(4 pix) x 16 out-tiles(16 outs as 4 groups of 4)
__global__ __launch_bounds__(256) void k1_ln_inproj(
    const float* __restrict__ x,     // (B,C,L)
    const float* __restrict__ ln1_g,
    const float* __restrict__ ln1_b,
    const float* __restrict__ ipw,   // (256,64)
    const float* __restrict__ ipb,   // (256)
    float* __restrict__ xi, float* __restrict__ zs)
{
    int bid = blockIdx.x;            // b*64 + ptile
    int b = bid >> 6, p0 = (bid & 63)*64;
    int tid = threadIdx.x;

    __shared__ float xs[64*65];      // xs[pix][c]
    __shared__ float lnxT[64*68];    // lnxT[c][pix]
    __shared__ float wT[16*260];     // chunk weights wT[k][d]
    __shared__ float gb[128];
    __shared__ float bias[256];
    __shared__ float red[512];
    __shared__ float mv[128];

    if (tid < 128) gb[tid] = (tid < 64) ? ln1_g[tid] : ln1_b[tid - 64];
    bias[tid] = ipb[tid];

    // stage x tile transposed: read coalesced over pixels, write xs[pix][c]
    #pragma unroll
    for (int it = 0; it < 4; it++){
        int i = tid + it*256;        // 1024 float4
        int c = i >> 4, pq = i & 15;
        float4 v = *(const float4*)(x + ((size_t)(b*CC + c))*LL + p0 + pq*4);
        xs[(pq*4+0)*65 + c] = v.x;
        xs[(pq*4+1)*65 + c] = v.y;
        xs[(pq*4+2)*65 + c] = v.z;
        xs[(pq*4+3)*65 + c] = v.w;
    }
    __syncthreads();

    // LN stats: thread = (pix, quarter of 16 c)
    {
        int pix = tid >> 2, q = tid & 3;
        float s = 0.f, sq = 0.f;
        #pragma unroll
        for (int cc = 0; cc < 16; cc++){
            float v = xs[pix*65 + q*16 + cc];
            s += v; sq = fmaf(v, v, sq);
        }
        red[tid*2] = s; red[tid*2+1] = sq;
    }
    __syncthreads();
    if (tid < 64){
        float s = red[tid*8] + red[tid*8+2] + red[tid*8+4] + red[tid*8+6];
        float sq = red[tid*8+1] + red[tid*8+3] + red[tid*8+5] + red[tid*8+7];
        float mean = s * (1.f/64.f);
        float var  = sq * (1.f/64.f) - mean*mean;
        mv[tid*2] = mean; mv[tid*2+1] = rsqrtf(var + 1e-5f);
    }
    __syncthreads();
    {
        int pix = tid >> 2, q = tid & 3;
        float mean = mv[pix*2], rstd = mv[pix*2+1];
        #pragma unroll
        for (int cc = 0; cc < 16; cc++){
            int c = q*16 + cc;
            float v = (xs[pix*65 + c] - mean)*rstd*gb[c] + gb[64+c];
            lnxT[c*68 + pix] = v;
        }
    }

    int pt = tid >> 4, ot = tid & 15;
    float acc[16][4];
    #pragma unroll
    for (int j = 0; j < 16; j++)
        #pragma unroll
        for (int i2 = 0; i2 < 4; i2++) acc[j][i2] = 0.f;

    for (int kc = 0; kc < 4; kc++){
        __syncthreads();
        // load weight chunk transposed: wT[k][d], k = 16 channels of this chunk
        #pragma unroll
        for (int it = 0; it < 4; it++){
            int i = tid + it*256;    // 1024 float4: 256 d x 4 quads
            int d = i >> 2, jq = i & 3;
            float4 wv = *(const float4*)(ipw + d*64 + kc*16 + jq*4);
            wT[(jq*4+0)*260 + d] = wv.x;
            wT[(jq*4+1)*260 + d] = wv.y;
            wT[(jq*4+2)*260 + d] = wv.z;
            wT[(jq*4+3)*260 + d] = wv.w;
        }
        __syncthreads();
        #pragma unroll
        for (int k = 0; k < 16; k++){
            float4 rv = *(const float4*)(lnxT + (kc*16 + k)*68 + pt*4);
            #pragma unroll
            for (int g = 0; g < 4; g++){
                float4 wv = *(const float4*)(wT + k*260 + g*64 + ot*4);
                acc[g*4+0][0] = fmaf(wv.x, rv.x, acc[g*4+0][0]);
                acc[g*4+0][1] = fmaf(wv.x, rv.y, acc[g*4+0][1]);
                acc[g*4+0][2] = fmaf(wv.x, rv.z, acc[g*4+0][2]);
                acc[g*4+0][3] = fmaf(wv.x, rv.w, acc[g*4+0][3]);
                acc[g*4+1][0] = fmaf(wv.y, rv.x, acc[g*4+1][0]);
                acc[g*4+1][1] = fmaf(wv.y, rv.y, acc[g*4+1][1]);
                acc[g*4+1][2] = fmaf(wv.y, rv.z, acc[g*4+1][2]);
                acc[g*4+1][3] = fmaf(wv.y, rv.w, acc[g*4+1][3]);
                acc[g*4+2][0] = fmaf(wv.z, rv.x, acc[g*4+2][0]);
                acc[g*4+2][1] = fmaf(wv.z, rv.y, acc[g*4+2][1]);
                acc[g*4+2][2] = fmaf(wv.z, rv.z, acc[g*4+2][2]);
                acc[g*4+2][3] = fmaf(wv.z, rv.w, acc[g*4+2][3]);
                acc[g*4+3][0] = fmaf(wv.w, rv.x, acc[g*4+3][0]);
                acc[g*4+3][1] = fmaf(wv.w, rv.y, acc[g*4+3][1]);
                acc[g*4+3][2] = fmaf(wv.w, rv.z, acc[g*4+3][2]);
                acc[g*4+3][3] = fmaf(wv.w, rv.w, acc[g*4+3][3]);
            }
        }
    }

    // epilogue: d = g*64 + ot*4 + jj ; g<2 -> xi, g>=2 -> silu -> zs
    #pragma unroll
    for (int i2 = 0; i2 < 4; i2++){
        size_t prow = ((size_t)(b*LL) + p0 + pt*4 + i2);
        #pragma unroll
        for (int g = 0; g < 4; g++){
            int dbase = g*64 + ot*4;
            float4 v;
            v.x = acc[g*4+0][i2] + bias[dbase+0];
            v.y = acc[g*4+1][i2] + bias[dbase+1];
            v.z = acc[g*4+2][i2] + bias[dbase+2];
            v.w = acc[g*4+3][i2] + bias[dbase+3];
            if (g < 2){
                *(float4*)(xi + prow*DI + dbase) = v;
            } else {
                v.x = v.x / (1.f + __expf(-v.x));
                v.y = v.y / (1.f + __expf(-v.y));
                v.z = v.z / (1.f + __expf(-v.z));
                v.w = v.w / (1.f + __expf(-v.w));
                *(float4*)(zs + prow*DI + dbase - 128) = v;
            }
        }
    }
}

// ---------------- K2: depthwise 3x3 + SiLU -> xc (B,L,DI)
__global__ __launch_bounds__(256) void k2_dwconv(
    const float* __restrict__ xi,
    const float* __restrict__ cw,   // (128,3,3)
    const float* __restrict__ cb,
    float* __restrict__ xc)
{
    int idx = blockIdx.x*256 + threadIdx.x;
    int d = idx & 127;
    int bp = idx >> 7;
    int p = bp & 4095, b = bp >> 12;
    int h = p >> 6, w = p & 63;
    float acc = cb[d];
    #pragma unroll
    for (int ky = 0; ky < 3; ky++){
        int hh = h + ky - 1;
        if ((unsigned)hh >= 64u) continue;
        #pragma unroll
        for (int kx = 0; kx < 3; kx++){
            int ww = w + kx - 1;
            if ((unsigned)ww >= 64u) continue;
            acc = fmaf(xi[((size_t)(b*LL) + hh*64 + ww)*DI + d], cw[d*9 + ky*3 + kx], acc);
        }
    }
    float sg = 1.f / (1.f + __expf(-acc));
    xc[idx] = acc * sg;
}

// ---------------- K3: x_dbl = xproj(xc), register-tiled LDS GEMM
__global__ __launch_bounds__(256) void k3_xdbl(
    const float* __restrict__ xc,
    const float* __restrict__ xpw,   // (144,128)
    float* __restrict__ xdbl)
{
    int bid = blockIdx.x;
    int b = bid >> 6, ptile = bid & 63;
    int tid = threadIdx.x;
    int ot = tid & 15;
    int pt = tid >> 4;

    __shared__ float r[64*132];
    __shared__ float wT[32*192];

    const float* xcb = xc + ((size_t)(b*LL) + ptile*64)*DI;
    for (int i = tid; i < 2048; i += 256){
        int pix = i >> 5, kq = i & 31;
        float4 v = *(const float4*)(xcb + pix*128 + kq*4);
        *(float4*)(r + pix*132 + kq*4) = v;
    }

    float acc[9][4];
    #pragma unroll
    for (int j = 0; j < 9; j++)
        #pragma unroll
        for (int i2 = 0; i2 < 4; i2++) acc[j][i2] = 0.f;

    for (int kc = 0; kc < 4; kc++){
        __syncthreads();
        int k0 = kc*32;
        for (int i = tid; i < 1152; i += 256){
            int cl = i >> 3, jq = i & 7;
            float4 wv = *(const float4*)(xpw + cl*128 + k0 + jq*4);
            int o = (cl*456) >> 12;
            int j = cl - o*9;
            wT[(jq*4+0)*192 + o*12 + j] = wv.x;
            wT[(jq*4+1)*192 + o*12 + j] = wv.y;
            wT[(jq*4+2)*192 + o*12 + j] = wv.z;
            wT[(jq*4+3)*192 + o*12 + j] = wv.w;
        }
        __syncthreads();
        const float* rbase = r + (pt*4)*132 + k0;
        #pragma unroll 4
        for (int k = 0; k < 32; k++){
            float4 wa = *(const float4*)(wT + k*192 + ot*12);
            float4 wb = *(const float4*)(wT + k*192 + ot*12 + 4);
            float w8 = wT[k*192 + ot*12 + 8];
            float rv0 = rbase[k];
            float rv1 = rbase[132 + k];
            float rv2 = rbase[264 + k];
            float rv3 = rbase[396 + k];
            float wv[9] = {wa.x, wa.y, wa.z, wa.w, wb.x, wb.y, wb.z, wb.w, w8};
            float rv[4] = {rv0, rv1, rv2, rv3};
            #pragma unroll
            for (int j = 0; j < 9; j++)
                #pragma unroll
                for (int i2 = 0; i2 < 4; i2++)
                    acc[j][i2] = fmaf(wv[j], rv[i2], acc[j][i2]);
        }
    }

    int kd = ot >> 2;
    int cbase = (ot & 3)*9;
    size_t obase = ((size_t)(b*KK + kd))*LL;
    #pragma unroll
    for (int i2 = 0; i2 < 4; i2++){
        int p = ptile*64 + pt*4 + i2;
        int tT = (p & 63)*64 + (p >> 6);
        int t = (kd == 0) ? p : (kd == 1) ? tT : (kd == 2) ? (4095 - p) : (4095 - tT);
        float* dst = xdbl + (obase + t)*XD + cbase;
        #pragma unroll
        for (int j = 0; j < 9; j++) dst[j] = acc[j][i2];
    }
}

// ---------------- K4a: per-chunk local scan -> H, P
__global__ __launch_bounds__(128, 4) void k4a_local(
    const float* __restrict__ xc, const float* __restrict__ xdbl,
    const float* __restrict__ dtw, const float* __restrict__ dtb,
    const float* __restrict__ A_logs,
    float* __restrict__ Pbuf, float* __restrict__ Hbuf)
{
    int bid = blockIdx.x;
    int cc = bid & 63, k = (bid >> 6) & 3, b = bid >> 8;
    int d = threadIdx.x;
    int kd = k*DI + d;
    float4 wv4 = *(const float4*)(dtw + kd*4);
    float bias = dtb[kd];
    float An[16];
    {
        const float4* al = (const float4*)(A_logs + kd*16);
        #pragma unroll
        for (int i = 0; i < 4; i++){
            float4 a = al[i];
            An[i*4+0] = -__expf(a.x); An[i*4+1] = -__expf(a.y);
            An[i*4+2] = -__expf(a.z); An[i*4+3] = -__expf(a.w);
        }
    }
    __shared__ float sraw[TT*XD];
    const float* src = xdbl + ((size_t)(b*KK + k)*LL + cc*TT)*XD;
    for (int i = threadIdx.x; i < TT*XD/4; i += 128)
        ((float4*)sraw)[i] = ((const float4*)src)[i];
    __syncthreads();

    const float* xcb = xc + (size_t)b*LL*DI;
    float h[16];
    #pragma unroll
    for (int i = 0; i < 16; i++) h[i] = 0.f;
    float Sdt = 0.f;
    for (int t = 0; t < TT; t++){
        const float* rp = sraw + t*XD;
        float4 xr = *(const float4*)rp;
        float dtr = fmaf(xr.x, wv4.x, fmaf(xr.y, wv4.y, fmaf(xr.z, wv4.z, fmaf(xr.w, wv4.w, bias))));
        float dt = softplusf(dtr);
        Sdt += dt;
        int p = p_of(k, cc*TT + t);
        float u = xcb[(size_t)p*DI + d];
        float du = dt * u;
        float4 B0 = *(const float4*)(rp + 4);
        float4 B1 = *(const float4*)(rp + 8);
        float4 B2 = *(const float4*)(rp + 12);
        float4 B3 = *(const float4*)(rp + 16);
        float Bv[16] = {B0.x,B0.y,B0.z,B0.w, B1.x,B1.y,B1.z,B1.w,
                        B2.x,B2.y,B2.z,B2.w, B3.x,B3.y,B3.z,B3.w};
        #pragma unroll
        for (int i = 0; i < 16; i++){
            float e = __expf(dt * An[i]);
            h[i] = fmaf(h[i], e, du * Bv[i]);
        }
    }
    size_t ob = ((size_t)bid)*2048 + d*16;
    #pragma unroll
    for (int i = 0; i < 16; i++){
        Pbuf[ob + i] = __expf(An[i] * Sdt);
        Hbuf[ob + i] = h[i];
    }
}

// ---------------- K4b: chunk-boundary propagation
__global__ __launch_bounds__(256) void k4b_prop(
    const float* __restrict__ Pbuf, const float* __restrict__ Hbuf,
    float* __restrict__ hin_buf)
{
    int chain = blockIdx.x*256 + threadIdx.x;
    int bk = chain >> 11, s = chain & 2047;
    float hin = 0.f;
    for (int c = 0; c < GG; c++){
        size_t idx = ((size_t)(bk*GG + c))*2048 + s;
        hin_buf[idx] = hin;
        hin = fmaf(Pbuf[idx], hin, Hbuf[idx]);
    }
}

// ---------------- K4c: per-chunk re-scan seeded with hin, emit y
__global__ __launch_bounds__(128, 4) void k4c_emit(
    const float* __restrict__ xc, const float* __restrict__ xdbl,
    const float* __restrict__ dtw, const float* __restrict__ dtb,
    const float* __restrict__ A_logs, const float* __restrict__ Ds,
    const float* __restrict__ hin_buf,
    float* __restrict__ y)
{
    int bid = blockIdx.x;
    int cc = bid & 63, k = (bid >> 6) & 3, b = bid >> 8;
    int d = threadIdx.x;
    int kd = k*DI + d;
    float4 wv4 = *(const float4*)(dtw + kd*4);
    float bias = dtb[kd];
    float Dv = Ds[kd];
    float An[16];
    {
        const float4* al = (const float4*)(A_logs + kd*16);
        #pragma unroll
        for (int i = 0; i < 4; i++){
            float4 a = al[i];
            An[i*4+0] = -__expf(a.x); An[i*4+1] = -__expf(a.y);
            An[i*4+2] = -__expf(a.z); An[i*4+3] = -__expf(a.w);
        }
    }
    __shared__ float sraw[TT*XD];
    const float* src = xdbl + ((size_t)(b*KK + k)*LL + cc*TT)*XD;
    for (int i = threadIdx.x; i < TT*XD/4; i += 128)
        ((float4*)sraw)[i] = ((const float4*)src)[i];
    __syncthreads();

    const float* xcb = xc + (size_t)b*LL*DI;
    float* yb = y + (size_t)b*LL*DI;
    float h[16];
    {
        const float4* hi = (const float4*)(hin_buf + ((size_t)bid)*2048 + d*16);
        #pragma unroll
        for (int i = 0; i < 4; i++){
            float4 a = hi[i];
            h[i*4+0] = a.x; h[i*4+1] = a.y; h[i*4+2] = a.z; h[i*4+3] = a.w;
        }
    }
    for (int t = 0; t < TT; t++){
        const float* rp = sraw + t*XD;
        float4 xr = *(const float4*)rp;
        float dtr = fmaf(xr.x, wv4.x, fmaf(xr.y, wv4.y, fmaf(xr.z, wv4.z, fmaf(xr.w, wv4.w, bias))));
        float dt = softplusf(dtr);
        int p = p_of(k, cc*TT + t);
        float u = xcb[(size_t)p*DI + d];
        float du = dt * u;
        float4 B0 = *(const float4*)(rp + 4);
        float4 B1 = *(const float4*)(rp + 8);
        float4 B2 = *(const float4*)(rp + 12);
        float4 B3 = *(const float4*)(rp + 16);
        float Bv[16] = {B0.x,B0.y,B0.z,B0.w, B1.x,B1.y,B1.z,B1.w,
                        B2.x,B2.y,B2.z,B2.w, B3.x,B3.y,B3.z,B3.w};
        float4 C0 = *(const float4*)(rp + 20);
        float4 C1 = *(const float4*)(rp + 24);
        float4 C2 = *(const float4*)(rp + 28);
        float4 C3 = *(const float4*)(rp + 32);
        float Cv[16] = {C0.x,C0.y,C0.z,C0.w, C1.x,C1.y,C1.z,C1.w,
                        C2.x,C2.y,C2.z,C2.w, C3.x,C3.y,C3.z,C3.w};
        float yv = Dv * u;
        #pragma unroll
        for (int i = 0; i < 16; i++){
            float e = __expf(dt * An[i]);
            h[i] = fmaf(h[i], e, du * Bv[i]);
            yv = fmaf(h[i], Cv[i], yv);
        }
        atomicAdd(&yb[(size_t)p*DI + d], yv);
    }
}

// ---------------- K4 serial fallback (used if ws too small)
__global__ __launch_bounds__(256) void k4_scan(
    const float* __restrict__ xc, const float* __restrict__ xdbl,
    const float* __restrict__ dtw, const float* __restrict__ dtb,
    const float* __restrict__ A_logs, const float* __restrict__ Ds,
    float* __restrict__ y)
{
    int bid = blockIdx.x;
    int b = bid >> 5, k = (bid >> 3) & 3, grp = bid & 7;
    int d0 = grp * 16;
    int tid = threadIdx.x;
    int wv = tid >> 6, lane = tid & 63, n = lane & 15, j = lane >> 4;
    int ch = wv*4 + j;
    int d = d0 + ch;
    int kd = k*DI + d;
    float An = -__expf(A_logs[kd*NN + n]);
    int ch_s = tid & 15;
    int kds = k*DI + d0 + ch_s;
    float w0s = dtw[kds*4+0], w1s = dtw[kds*4+1], w2s = dtw[kds*4+2], w3s = dtw[kds*4+3];
    float bs  = dtb[kds];
    float Dvs = Ds[kds];
    __shared__ float sraw[64*XD];
    __shared__ float sdd[64*16*2];
    __shared__ float sdy[64*17];
    const float* xdbase = xdbl + (size_t)(b*KK + k)*LL*XD;
    const float* xcb = xc + (size_t)b*LL*DI;
    float* yb = y + (size_t)b*LL*DI;
    float h = 0.f;
    for (int cc = 0; cc < 64; cc++){
        __syncthreads();
        const float* src = xdbase + (size_t)cc*64*XD;
        for (int i2 = tid; i2 < 576; i2 += 256)
            ((float4*)sraw)[i2] = ((const float4*)src)[i2];
        #pragma unroll
        for (int it = 0; it < 4; it++){
            int idx = tid + it*256;
            int t = idx >> 4;
            int pu = p_of(k, cc*64 + t);
            float u = xcb[(size_t)pu*DI + d0 + ch_s];
            float4 xr = *(const float4*)(src + t*XD);
            float dtr = fmaf(xr.x, w0s, fmaf(xr.y, w1s, fmaf(xr.z, w2s, fmaf(xr.w, w3s, bs))));
            float dt = softplusf(dtr);
            sdd[idx*2]     = dt;
            sdd[idx*2 + 1] = dt*u;
            sdy[t*17 + ch_s] = Dvs * u;
        }
        __syncthreads();
        #pragma unroll
        for (int tg = 0; tg < 4; tg++){
            float myv = 0.f;
            #pragma unroll
            for (int it = 0; it < 16; it++){
                int t = tg*16 + it;
                float dt = sdd[(t*16 + ch)*2];
                float du = sdd[(t*16 + ch)*2 + 1];
                float Bn = sraw[t*XD + 4 + n];
                float Cn = sraw[t*XD + 20 + n];
                float e = __expf(dt * An);
                h = fmaf(h, e, du * Bn);
                float yv = h * Cn;
                yv = dpp_xadd<0xB1>(yv);
                yv = dpp_xadd<0x4E>(yv);
                yv = dpp_xadd<0x141>(yv);
                yv = dpp_xadd<0x140>(yv);
                if (it == n) myv = yv;
            }
            int t = tg*16 + n;
            float yt = myv + sdy[t*17 + ch];
            int p = p_of(k, cc*64 + t);
            atomicAdd(&yb[(size_t)p*DI + d], yt);
        }
    }
}

// ---------------- K5: outnorm LN(DI)*silu(z) + out_proj + residual, tiled GEMM
// block = 64 pixels; 256 thr; out tile: 4 pix x 4 c
__global__ __launch_bounds__(256) void k5_out(
    const float* __restrict__ y, const float* __restrict__ zs,
    const float* __restrict__ on_g, const float* __restrict__ on_b,
    const float* __restrict__ opw,  // (64,128)
    const float* __restrict__ opb,
    const float* __restrict__ x,    // (B,C,L)
    float* __restrict__ xo)
{
    int bid = blockIdx.x;
    int b = bid >> 6, p0 = (bid & 63)*64;
    int tid = threadIdx.x;

    __shared__ float vT[128*68];     // vT[d][pix]
    __shared__ float wT[128*68];     // wT[d][c]
    __shared__ float gb[256];        // g 0..127, b 128..255
    __shared__ float ob[64];
    __shared__ float red[512];
    __shared__ float mv[128];

    gb[tid] = (tid < 128) ? on_g[tid] : on_b[tid - 128];
    if (tid < 64) ob[tid] = opb[tid];

    // stage opw transposed
    #pragma unroll
    for (int it = 0; it < 8; it++){
        int i = tid + it*256;        // 2048 float4: 64 c x 32 quads
        int c = i >> 5, jq = i & 31;
        float4 wv = *(const float4*)(opw + c*128 + jq*4);
        wT[(jq*4+0)*68 + c] = wv.x;
        wT[(jq*4+1)*68 + c] = wv.y;
        wT[(jq*4+2)*68 + c] = wv.z;
        wT[(jq*4+3)*68 + c] = wv.w;
    }

    // LN stats + gated value, thread = (pix, quarter of 32 d)
    int pix = tid >> 2, q = tid & 3;
    size_t base = ((size_t)(b*LL) + p0 + pix)*DI + q*32;
    float yv[32];
    {
        const float4* y4 = (const float4*)(y + base);
        float s = 0.f, sq = 0.f;
        #pragma unroll
        for (int i = 0; i < 8; i++){
            float4 a = y4[i];
            yv[i*4+0] = a.x; yv[i*4+1] = a.y; yv[i*4+2] = a.z; yv[i*4+3] = a.w;
            s += a.x + a.y + a.z + a.w;
            sq = fmaf(a.x,a.x, fmaf(a.y,a.y, fmaf(a.z,a.z, fmaf(a.w,a.w, sq))));
        }
        red[tid*2] = s; red[tid*2+1] = sq;
    }
    __syncthreads();
    if (tid < 64){
        float s = red[tid*8] + red[tid*8+2] + red[tid*8+4] + red[tid*8+6];
        float sq = red[tid*8+1] + red[tid*8+3] + red[tid*8+5] + red[tid*8+7];
        float mean = s * (1.f/128.f);
        float var  = sq * (1.f/128.f) - mean*mean;
        mv[tid*2] = mean; mv[tid*2+1] = rsqrtf(var + 1e-5f);
    }
    __syncthreads();
    {
        float mean = mv[pix*2], rstd = mv[pix*2+1];
        const float4* z4 = (const float4*)(zs + base);
        #pragma unroll
        for (int i = 0; i < 8; i++){
            float4 zz = z4[i];
            float zv[4] = {zz.x, zz.y, zz.z, zz.w};
            #pragma unroll
            for (int jj = 0; jj < 4; jj++){
                int d = q*32 + i*4 + jj;
                float vn = (yv[i*4+jj] - mean)*rstd*gb[d] + gb[128+d];
                vT[d*68 + pix] = vn * zv[jj];
            }
        }
    }
    __syncthreads();

    int pt = tid >> 4, ot = tid & 15;
    float acc[4][4];
    #pragma unroll
    for (int j = 0; j < 4; j++)
        #pragma unroll
        for (int i2 = 0; i2 < 4; i2++) acc[j][i2] = 0.f;

    #pragma unroll 4
    for (int k = 0; k < 128; k++){
        float4 rv = *(const float4*)(vT + k*68 + pt*4);
        float4 wv = *(const float4*)(wT + k*68 + ot*4);
        acc[0][0] = fmaf(wv.x, rv.x, acc[0][0]); acc[0][1] = fmaf(wv.x, rv.y, acc[0][1]);
        acc[0][2] = fmaf(wv.x, rv.z, acc[0][2]); acc[0][3] = fmaf(wv.x, rv.w, acc[0][3]);
        acc[1][0] = fmaf(wv.y, rv.x, acc[1][0]); acc[1][1] = fmaf(wv.y, rv.y, acc[1][1]);
        acc[1][2] = fmaf(wv.y, rv.z, acc[1][2]); acc[1][3] = fmaf(wv.y, rv.w, acc[1][3]);
        acc[2][0] = fmaf(wv.z, rv.x, acc[2][0]); acc[2][1] = fmaf(wv.z, rv.y, acc[2][1]);
        acc[2][2] = fmaf(wv.z, rv.z, acc[2][2]); acc[2][3] = fmaf(wv.z, rv.w, acc[2][3]);
        acc[3][0] = fmaf(wv.w, rv.x, acc[3][0]); acc[3][1] = fmaf(wv.w, rv.y, acc[3][1]);
        acc[3][2] = fmaf(wv.w, rv.z, acc[3][2]); acc[3][3] = fmaf(wv.w, rv.w, acc[3][3]);
    }

    // epilogue: + opb + residual x, write xo pixel-major
    #pragma unroll
    for (int jj = 0; jj < 4; jj++){
        int c = ot*4 + jj;
        float4 xr = *(const float4*)(x + ((size_t)(b*CC + c))*LL + p0 + pt*4);
        acc[jj][0] += ob[c] + xr.x;
        acc[jj][1] += ob[c] + xr.y;
        acc[jj][2] += ob[c] + xr.z;
        acc[jj][3] += ob[c] + xr.w;
    }
    #pragma unroll
    for (int i2 = 0; i2 < 4; i2++){
        float4 v = make_float4(acc[0][i2], acc[1][i2], acc[2][i2], acc[3][i2]);
        *(float4*)(xo + ((size_t)(b*LL) + p0 + pt*4 + i2)*CC + ot*4) = v;
    }
}

// ---------------- K6: channel LayerNorm over C -> cl (B,L,C), 4 thr/pixel
__global__ __launch_bounds__(256) void k6_chln(
    const float* __restrict__ xo,
    const float* __restrict__ cn_g, const float* __restrict__ cn_b,
    float* __restrict__ cl)
{
    int t = blockIdx.x*256 + threadIdx.x;     // 131072 = 32768 pix x 4
    int pix = t >> 2, q = t & 3;
    const float4* r4 = (const float4*)(xo + (size_t)pix*CC + q*16);
    float4 a[4];
    float s = 0.f, sq = 0.f;
    #pragma unroll
    for (int i = 0; i < 4; i++){
        a[i] = r4[i];
        s += a[i].x + a[i].y + a[i].z + a[i].w;
        sq = fmaf(a[i].x,a[i].x, fmaf(a[i].y,a[i].y, fmaf(a[i].z,a[i].z, fmaf(a[i].w,a[i].w, sq))));
    }
    s += __shfl_xor(s, 1, 64);  sq += __shfl_xor(sq, 1, 64);
    s += __shfl_xor(s, 2, 64);  sq += __shfl_xor(sq, 2, 64);
    float mean = s * (1.f/64.f);
    float var  = sq * (1.f/64.f) - mean*mean;
    float rstd = rsqrtf(var + 1e-6f);
    const float4* g4 = (const float4*)(cn_g + q*16);
    const float4* b4 = (const float4*)(cn_b + q*16);
    float4* o4 = (float4*)(cl + (size_t)pix*CC + q*16);
    #pragma unroll
    for (int i = 0; i < 4; i++){
        float4 g = g4[i], bb = b4[i], r;
        r.x = (a[i].x - mean)*rstd*g.x + bb.x;
        r.y = (a[i].y - mean)*rstd*g.y + bb.y;
        r.z = (a[i].z - mean)*rstd*g.z + bb.z;
        r.w = (a[i].w - mean)*rstd*g.w + bb.w;
        o4[i] = r;
    }
}

// ---------------- K7: max pools 2/4/8 for SAFM branches 1..3
__global__ __launch_bounds__(256) void k7_pools(const float* __restrict__ cl, float* __restrict__ pools)
{
    int idx = blockIdx.x*256 + threadIdx.x;
    int g, S, base;
    if (idx < 131072)      { g = 1; S = 32; base = 0; }
    else if (idx < 163840) { g = 2; S = 16; base = 131072; idx -= 131072; }
    else if (idx < 172032) { g = 3; S = 8;  base = 163840; idx -= 163840; }
    else return;
    int pw = idx % S; idx /= S;
    int ph = idx % S; idx /= S;
    int j = idx & 15; int b = idx >> 4;
    int kk = 64 / S;
    int c = g*16 + j;
    float m = -1e30f;
    for (int dy = 0; dy < kk; dy++)
        for (int dx = 0; dx < kk; dx++){
            int h = ph*kk + dy, w = pw*kk + dx;
            m = fmaxf(m, cl[((size_t)(b*LL) + h*64 + w)*CC + c]);
        }
    pools[base + ((size_t)(b*16 + j)*S + ph)*S + pw] = m;
}

// ---------------- K8: SAFM branch depthwise convs -> cat (B,L,C)
__global__ __launch_bounds__(256) void k8_mfr(
    const float* __restrict__ cl, const float* __restrict__ pools,
    const float* __restrict__ mfr_w,  // (4,16,3,3)
    const float* __restrict__ mfr_b,  // (4,16)
    float* __restrict__ cat)
{
    int idx = blockIdx.x*256 + threadIdx.x;
    int c = idx & 63; int bp = idx >> 6;
    int p = bp & 4095, b = bp >> 12;
    int g = c >> 4, j = c & 15;
    int h = p >> 6, w = p & 63;
    float acc = mfr_b[g*16 + j];
    const float* wr = mfr_w + (g*16 + j)*9;
    if (g == 0){
        #pragma unroll
        for (int ky = 0; ky < 3; ky++){
            int hh = h + ky - 1; if ((unsigned)hh >= 64u) continue;
            #pragma unroll
            for (int kx = 0; kx < 3; kx++){
                int ww = w + kx - 1; if ((unsigned)ww >= 64u) continue;
                acc = fmaf(cl[((size_t)(b*LL) + hh*64 + ww)*CC + c], wr[ky*3 + kx], acc);
            }
        }
    } else {
        int S = 64 >> g;
        int ph = h >> g, pw = w >> g;
        int base = (g == 1) ? 0 : ((g == 2) ? 131072 : 163840);
        const float* P = pools + base + (size_t)(b*16 + j)*S*S;
        #pragma unroll
        for (int ky = 0; ky < 3; ky++){
            int hh = ph + ky - 1; if ((unsigned)hh >= (unsigned)S) continue;
            #pragma unroll
            for (int kx = 0; kx < 3; kx++){
                int ww = pw + kx - 1; if ((unsigned)ww >= (unsigned)S) continue;
                acc = fmaf(P[hh*S + ww], wr[ky*3 + kx], acc);
            }
        }
    }
    cat[idx] = acc;
}

// ---------------- K9: 1x1 agg + GELU*cl + residual, tiled GEMM -> out (B,C,L)
__global__ __launch_bounds__(256) void k9_agg(
    const float* __restrict__ cat, const float* __restrict__ cl, const float* __restrict__ xo,
    const float* __restrict__ agw,   // (64,64)
    const float* __restrict__ agb,
    float* __restrict__ out)
{
    int bid = blockIdx.x;
    int b = bid >> 6, p0 = (bid & 63)*64;
    int tid = threadIdx.x;

    __shared__ float catT[64*68];    // catT[c][pix]
    __shared__ float wT[64*68];      // wT[c][o]
    __shared__ float ab[64];

    if (tid < 64) ab[tid] = agb[tid];
    #pragma unroll
    for (int it = 0; it < 4; it++){
        int i = tid + it*256;        // 1024 f4: 64 pix x 16 quads
        int pix = i >> 4, cq = i & 15;
        float4 v = *(const float4*)(cat + ((size_t)(b*LL) + p0 + pix)*CC + cq*4);
        catT[(cq*4+0)*68 + pix] = v.x;
        catT[(cq*4+1)*68 + pix] = v.y;
        catT[(cq*4+2)*68 + pix] = v.z;
        catT[(cq*4+3)*68 + pix] = v.w;
        int o = i >> 4;              // 64 o x 16 quads
        float4 wv = *(const float4*)(agw + o*64 + cq*4);
        wT[(cq*4+0)*68 + o] = wv.x;
        wT[(cq*4+1)*68 + o] = wv.y;
        wT[(cq*4+2)*68 + o] = wv.z;
        wT[(cq*4+3)*68 + o] = wv.w;
    }
    __syncthreads();

    int pt = tid >> 4, ot = tid & 15;
    float acc[4][4];
    #pragma unroll
    for (int j = 0; j < 4; j++)
        #pragma unroll
        for (int i2 = 0; i2 < 4; i2++) acc[j][i2] = 0.f;

    #pragma unroll 4
    for (int k = 0; k < 64; k++){
        float4 rv = *(const float4*)(catT + k*68 + pt*4);
        float4 wv = *(const float4*)(wT + k*68 + ot*4);
        acc[0][0] = fmaf(wv.x, rv.x, acc[0][0]); acc[0][1] = fmaf(wv.x, rv.y, acc[0][1]);
        acc[0][2] = fmaf(wv.x, rv.z, acc[0][2]); acc[0][3] = fmaf(wv.x, rv.w, acc[0][3]);
        acc[1][0] = fmaf(wv.y, rv.x, acc[1][0]); acc[1][1] = fmaf(wv.y, rv.y, acc[1][1]);
        acc[1][2] = fmaf(wv.y, rv.z, acc[1][2]); acc[1][3] = fmaf(wv.y, rv.w, acc[1][3]);
        acc[2][0] = fmaf(wv.z, rv.x, acc[2][0]); acc[2][1] = fmaf(wv.z, rv.y, acc[2][1]);
        acc[2][2] = fmaf(wv.z, rv.z, acc[2][2]); acc[2][3] = fmaf(wv.z, rv.w, acc[2][3]);
        acc[3][0] = fmaf(wv.w, rv.x, acc[3][0]); acc[3][1] = fmaf(wv.w, rv.y, acc[3][1]);
        acc[3][2] = fmaf(wv.w, rv.z, acc[3][2]); acc[3][3] = fmaf(wv.w, rv.w, acc[3][3]);
    }

    // epilogue: gelu(acc+agb) * cl + xo, store (B,C,L) coalesced over pixels
    float res[4][4];                 // [o][pix]
    #pragma unroll
    for (int i2 = 0; i2 < 4; i2++){
        size_t prow = ((size_t)(b*LL) + p0 + pt*4 + i2)*CC + ot*4;
        float4 clv = *(const float4*)(cl + prow);
        float4 xov = *(const float4*)(xo + prow);
        float cla[4] = {clv.x, clv.y, clv.z, clv.w};
        float xoa[4] = {xov.x, xov.y, xov.z, xov.w};
        #pragma unroll
        for (int jj = 0; jj < 4; jj++){
            float av = acc[jj][i2] + ab[ot*4 + jj];
            float gl = 0.5f*av*(1.f + erff(av*0.70710678118f));
            res[jj][i2] = xoa[jj] + gl*cla[jj];
        }
    }
    #pragma unroll
    for (int jj = 0; jj < 4; jj++){
        int o = ot*4 + jj;
        float4 v = make_float4(res[jj][0], res[jj][1], res[jj][2], res[jj][3]);
        *(float4*)(out + ((size_t)(b*CC + o))*LL + p0 + pt*4) = v;
    }
}

extern "C" void kernel_launch(void* const* d_in, const int* in_sizes, int n_in,
                              void* d_out, int out_size, void* d_ws, size_t ws_size,
                              hipStream_t stream)
{
    const float* x       = (const float*)d_in[0];
    const float* ln1_g   = (const float*)d_in[1];
    const float* ln1_b   = (const float*)d_in[2];
    const float* ipw     = (const float*)d_in[3];
    const float* ipb     = (const float*)d_in[4];
    const float* conv_w  = (const float*)d_in[5];
    const float* conv_b  = (const float*)d_in[6];
    const float* xpw     = (const float*)d_in[7];
    const float* dtw     = (const float*)d_in[8];
    const float* dtb     = (const float*)d_in[9];
    const float* A_logs  = (const float*)d_in[10];
    const float* Ds      = (const float*)d_in[11];
    const float* on_g    = (const float*)d_in[12];
    const float* on_b    = (const float*)d_in[13];
    const float* opw     = (const float*)d_in[14];
    const float* opb     = (const float*)d_in[15];
    const float* mfr_w   = (const float*)d_in[16];
    const float* mfr_b   = (const float*)d_in[17];
    const float* agw     = (const float*)d_in[18];
    const float* agb     = (const float*)d_in[19];
    const float* cn_g    = (const float*)d_in[20];
    const float* cn_b    = (const float*)d_in[21];
    float* out = (float*)d_out;

    float* ws = (float*)d_ws;
    float* xi    = ws;               // reused as y
    float* zs    = ws + 4194304;     // reused as cat
    float* xc    = ws + 8388608;     // reused as xo + pools
    float* xdbl  = ws + 12582912;    // reused as cl
    float* y     = xi;
    float* xo    = xc;
    float* pools = xc + 2097152;
    float* cl    = xdbl;
    float* cat   = zs;
    float* Pbuf  = ws + 17301504;
    float* Hbuf  = ws + 21495808;
    float* hinb  = ws + 25690112;
    bool par = ws_size >= (size_t)29884416 * 4;

    // SS2D
    hipLaunchKernelGGL(k1_ln_inproj, dim3(BB*64), dim3(256), 0, stream,
                       x, ln1_g, ln1_b, ipw, ipb, xi, zs);
    hipLaunchKernelGGL(k2_dwconv, dim3(BB*LL*DI/256), dim3(256), 0, stream,
                       xi, conv_w, conv_b, xc);
    hipLaunchKernelGGL(k3_xdbl, dim3(BB*64), dim3(256), 0, stream,
                       xc, xpw, xdbl);
    hipMemsetAsync(y, 0, (size_t)BB*LL*DI*sizeof(float), stream);
    if (par){
        hipLaunchKernelGGL(k4a_local, dim3(BB*KK*GG), dim3(128), 0, stream,
                           xc, xdbl, dtw, dtb, A_logs, Pbuf, Hbuf);
        hipLaunchKernelGGL(k4b_prop, dim3(256), dim3(256), 0, stream,
                           Pbuf, Hbuf, hinb);
        hipLaunchKernelGGL(k4c_emit, dim3(BB*KK*GG), dim3(128), 0, stream,
                           xc, xdbl, dtw, dtb, A_logs, Ds, hinb, y);
    } else {
        hipLaunchKernelGGL(k4_scan, dim3(256), dim3(256), 0, stream,
                           xc, xdbl, dtw, dtb, A_logs, Ds, y);
    }
    hipLaunchKernelGGL(k5_out, dim3(BB*64), dim3(256), 0, stream,
                       y, zs, on_g, on_b, opw, opb, x, xo);
    // SAFM
    hipLaunchKernelGGL(k6_chln, dim3(BB*LL*4/256), dim3(256), 0, stream,
                       xo, cn_g, cn_b, cl);
    hipLaunchKernelGGL(k7_pools, dim3((172032 + 255)/256), dim3(256), 0, stream,
                       cl, pools);
    hipLaunchKernelGGL(k8_mfr, dim3(BB*LL*CC/256), dim3(256), 0, stream,
                       cl, pools, mfr_w, mfr_b, cat);
    hipLaunchKernelGGL(k9_agg, dim3(BB*64), dim3(256), 0, stream,
                       cat, cl, xo, agw, agb, out);
}